// Round 9
// baseline (3004.926 us; speedup 1.0000x reference)
//
#include <hip/hip_runtime.h>

#define NN 100000
#define EE 3200000
#define EPSF 1e-5f

typedef unsigned short u16;
typedef short bf16x8 __attribute__((ext_vector_type(8)));
typedef float f32x4 __attribute__((ext_vector_type(4)));

static inline int cdiv(int a, int b) { return (a + b - 1) / b; }

__device__ __forceinline__ float b2f(u16 u) {
    return __uint_as_float((unsigned int)u << 16);
}
__device__ __forceinline__ u16 f2b(float f) {
    unsigned int i = __float_as_uint(f);
    return (u16)((i + 0x7FFFu + ((i >> 16) & 1u)) >> 16);  // RNE
}
// packed edge: [31:17] = positive float top bits, [16:0] = src index
__device__ __forceinline__ int ep_src(unsigned int p) { return (int)(p & 0x1FFFFu); }
__device__ __forceinline__ float ep_w(unsigned int p) {
    return __uint_as_float(p & 0xFFFE0000u);
}
// pack high16(f0) | high16(f1)<<16 — exact bf16 for values exactly representable (fp8 set)
__device__ __forceinline__ unsigned pkhi(float f0, float f1) {
    return __builtin_amdgcn_perm(__float_as_uint(f1), __float_as_uint(f0), 0x07060302u);
}

// ---------------- zero-init (graph-capture-safe) ----------------
__global__ void k_init(int* __restrict__ deg, int* __restrict__ cursor,
                       float* __restrict__ stats) {
    int i = blockIdx.x * 256 + threadIdx.x;
    if (i < NN) {
        deg[i] = 0;
        cursor[i] = 0;
    }
    if (i < 2048) stats[i] = 0.f;
}

// ---------------- degree histogram ----------------
__global__ void k_deg(const int* __restrict__ col, int* __restrict__ deg) {
    int i = blockIdx.x * 256 + threadIdx.x;
    if (i < EE) atomicAdd(&deg[col[i]], 1);
}

__global__ void k_dinv(const int* __restrict__ deg, float* __restrict__ dinv) {
    int i = blockIdx.x * 256 + threadIdx.x;
    if (i < NN) {
        int d = deg[i];
        dinv[i] = d > 0 ? rsqrtf((float)d) : 0.f;
    }
}

// ------- exclusive scan: 1024 threads, 98 contiguous elems per thread -------
__global__ void k_scan(const int* __restrict__ deg, int* __restrict__ offs) {
    __shared__ int sh[1024];
    int tid = threadIdx.x;
    int start = tid * 98;
    int end = min(start + 98, NN);
    int sum = 0;
    for (int i = start; i < end; ++i) sum += deg[i];
    sh[tid] = sum;
    __syncthreads();
    for (int off = 1; off < 1024; off <<= 1) {
        int t = (tid >= off) ? sh[tid - off] : 0;
        __syncthreads();
        sh[tid] += t;
        __syncthreads();
    }
    int base = tid ? sh[tid - 1] : 0;
    for (int i = start; i < end; ++i) {
        offs[i] = base;
        base += deg[i];
    }
    if (tid == 1023) offs[NN] = sh[1023];
}

// ---------------- CSR scatter: pack (w:15 | src:17) into one u32 ----------------
__global__ void k_scatter(const int* __restrict__ row, const int* __restrict__ col,
                          const float* __restrict__ dinv, const int* __restrict__ offs,
                          int* __restrict__ cursor, unsigned int* __restrict__ ep) {
    int i = blockIdx.x * 256 + threadIdx.x;
    if (i < EE) {
        int c = col[i], r = row[i];
        int pos = offs[c] + atomicAdd(&cursor[c], 1);
        float w = dinv[r] * dinv[c];  // >= 0
        unsigned int u = __float_as_uint(w);
        unsigned int rb = (u + 0xFFFFu + ((u >> 17) & 1u)) & 0xFFFE0000u;  // RNE @ 7-bit man
        ep[pos] = rb | (unsigned int)r;
    }
}

// ---------------- convert fp32 array -> bf16 (n4 = count of float4s) ----------------
__global__ void k_cvt(const float* __restrict__ src, u16* __restrict__ dst, int n4) {
    int idx = blockIdx.x * 256 + threadIdx.x;
    if (idx >= n4) return;
    float4 v = ((const float4*)src)[idx];
    ushort4 o;
    o.x = f2b(v.x);
    o.y = f2b(v.y);
    o.z = f2b(v.z);
    o.w = f2b(v.w);
    ((ushort4*)dst)[idx] = o;
}

// ---- convert a width-256 bf16 slice (lds_ elems) -> fp8 (ldd bytes), sequential ----
__global__ void k_cvt8s(const u16* __restrict__ src, int lds_, unsigned char* __restrict__ dst,
                        int ldd) {
    int idx = blockIdx.x * 256 + threadIdx.x;  // over NN*128 (2 elems each)
    if (idx >= NN * 128) return;
    int node = idx >> 7, f2 = (idx & 127) << 1;
    ushort2 v = *(const ushort2*)(src + (size_t)node * lds_ + f2);
    int pk = __builtin_amdgcn_cvt_pk_fp8_f32(b2f(v.x), b2f(v.y), 0, false);
    uchar2 o;
    o.x = (unsigned char)(pk & 0xFF);
    o.y = (unsigned char)((pk >> 8) & 0xFF);
    *(uchar2*)(dst + (size_t)node * ldd + f2) = o;
}

// ---- gather propagation, width 128, 64 thr/node (r7 proven config), fp8 out.
// S8: source fp8 (ldin in bytes) else bf16 (ldin in elems). ----
template <int S8>
__global__ void k_prop_t(const void* __restrict__ in, int ldin,
                         unsigned char* __restrict__ out8, int ldo8,
                         const int* __restrict__ offs, const unsigned int* __restrict__ ep) {
    int node = blockIdx.x;
    int f2 = threadIdx.x << 1;
    int s = offs[node], e = offs[node + 1];
    const u16* inb = (const u16*)in;
    const unsigned char* in8 = (const unsigned char*)in;
    float a0 = 0.f, a1 = 0.f;
    int t = s;
    for (; t + 4 <= e; t += 4) {
        unsigned int p0 = ep[t], p1 = ep[t + 1], p2 = ep[t + 2], p3 = ep[t + 3];
        float x0, y0, x1, y1, x2, y2, x3, y3;
        if (S8) {
            uchar2 c0 = *(const uchar2*)(in8 + (size_t)ep_src(p0) * ldin + f2);
            uchar2 c1 = *(const uchar2*)(in8 + (size_t)ep_src(p1) * ldin + f2);
            uchar2 c2 = *(const uchar2*)(in8 + (size_t)ep_src(p2) * ldin + f2);
            uchar2 c3 = *(const uchar2*)(in8 + (size_t)ep_src(p3) * ldin + f2);
            int w0 = c0.x | (c0.y << 8), w1 = c1.x | (c1.y << 8);
            int w2 = c2.x | (c2.y << 8), w3 = c3.x | (c3.y << 8);
            x0 = __builtin_amdgcn_cvt_f32_fp8(w0, 0);
            y0 = __builtin_amdgcn_cvt_f32_fp8(w0, 1);
            x1 = __builtin_amdgcn_cvt_f32_fp8(w1, 0);
            y1 = __builtin_amdgcn_cvt_f32_fp8(w1, 1);
            x2 = __builtin_amdgcn_cvt_f32_fp8(w2, 0);
            y2 = __builtin_amdgcn_cvt_f32_fp8(w2, 1);
            x3 = __builtin_amdgcn_cvt_f32_fp8(w3, 0);
            y3 = __builtin_amdgcn_cvt_f32_fp8(w3, 1);
        } else {
            ushort2 v0 = *(const ushort2*)(inb + (size_t)ep_src(p0) * ldin + f2);
            ushort2 v1 = *(const ushort2*)(inb + (size_t)ep_src(p1) * ldin + f2);
            ushort2 v2 = *(const ushort2*)(inb + (size_t)ep_src(p2) * ldin + f2);
            ushort2 v3 = *(const ushort2*)(inb + (size_t)ep_src(p3) * ldin + f2);
            x0 = b2f(v0.x);
            y0 = b2f(v0.y);
            x1 = b2f(v1.x);
            y1 = b2f(v1.y);
            x2 = b2f(v2.x);
            y2 = b2f(v2.y);
            x3 = b2f(v3.x);
            y3 = b2f(v3.y);
        }
        float w0 = ep_w(p0), w1 = ep_w(p1), w2 = ep_w(p2), w3 = ep_w(p3);
        a0 = fmaf(w0, x0, a0);
        a1 = fmaf(w0, y0, a1);
        a0 = fmaf(w1, x1, a0);
        a1 = fmaf(w1, y1, a1);
        a0 = fmaf(w2, x2, a0);
        a1 = fmaf(w2, y2, a1);
        a0 = fmaf(w3, x3, a0);
        a1 = fmaf(w3, y3, a1);
    }
    for (; t < e; ++t) {
        unsigned int p0 = ep[t];
        float x0, y0;
        if (S8) {
            uchar2 c0 = *(const uchar2*)(in8 + (size_t)ep_src(p0) * ldin + f2);
            int w = c0.x | (c0.y << 8);
            x0 = __builtin_amdgcn_cvt_f32_fp8(w, 0);
            y0 = __builtin_amdgcn_cvt_f32_fp8(w, 1);
        } else {
            ushort2 v0 = *(const ushort2*)(inb + (size_t)ep_src(p0) * ldin + f2);
            x0 = b2f(v0.x);
            y0 = b2f(v0.y);
        }
        float w0 = ep_w(p0);
        a0 = fmaf(w0, x0, a0);
        a1 = fmaf(w0, y0, a1);
    }
    int pk = __builtin_amdgcn_cvt_pk_fp8_f32(a0, a1, 0, false);
    uchar2 o8;
    o8.x = (unsigned char)(pk & 0xFF);
    o8.y = (unsigned char)((pk >> 8) & 0xFF);
    *(uchar2*)(out8 + (size_t)node * ldo8 + f2) = o8;
}

// ---- width-256 fp8 propagation: one wave/node, 4 cols/lane, 4x unroll (r7 proven) ----
__global__ void k_prop256(const unsigned char* __restrict__ in, int ldin,
                          unsigned char* __restrict__ out, int ldout,
                          const int* __restrict__ offs, const unsigned int* __restrict__ ep) {
    int node = blockIdx.x;
    int f4 = threadIdx.x << 2;
    int s = offs[node], e = offs[node + 1];
    float a0 = 0, a1 = 0, a2 = 0, a3 = 0;
    int t = s;
    for (; t + 4 <= e; t += 4) {
        unsigned int p[4];
        unsigned int v[4];
#pragma unroll
        for (int u = 0; u < 4; ++u) p[u] = ep[t + u];
#pragma unroll
        for (int u = 0; u < 4; ++u)
            v[u] = *(const unsigned int*)(in + (size_t)ep_src(p[u]) * ldin + f4);
#pragma unroll
        for (int u = 0; u < 4; ++u) {
            float w = ep_w(p[u]);
            a0 = fmaf(w, __builtin_amdgcn_cvt_f32_fp8((int)v[u], 0), a0);
            a1 = fmaf(w, __builtin_amdgcn_cvt_f32_fp8((int)v[u], 1), a1);
            a2 = fmaf(w, __builtin_amdgcn_cvt_f32_fp8((int)v[u], 2), a2);
            a3 = fmaf(w, __builtin_amdgcn_cvt_f32_fp8((int)v[u], 3), a3);
        }
    }
    for (; t < e; ++t) {
        unsigned int p0 = ep[t];
        unsigned int v = *(const unsigned int*)(in + (size_t)ep_src(p0) * ldin + f4);
        float w = ep_w(p0);
        a0 = fmaf(w, __builtin_amdgcn_cvt_f32_fp8((int)v, 0), a0);
        a1 = fmaf(w, __builtin_amdgcn_cvt_f32_fp8((int)v, 1), a1);
        a2 = fmaf(w, __builtin_amdgcn_cvt_f32_fp8((int)v, 2), a2);
        a3 = fmaf(w, __builtin_amdgcn_cvt_f32_fp8((int)v, 3), a3);
    }
    int p01 = __builtin_amdgcn_cvt_pk_fp8_f32(a0, a1, 0, false);
    int p23 = __builtin_amdgcn_cvt_pk_fp8_f32(a2, a3, 0, false);
    unsigned int o = (unsigned)(p01 & 0xFFFF) | ((unsigned)p23 << 16);
    *(unsigned int*)(out + (size_t)node * ldout + f4) = o;
}

// ---- width-16 fp32 propagation with addend (Horner), 16 nodes/block, 8x unroll ----
__global__ void k_prop16(const float* __restrict__ in, int ldin,
                         const float* __restrict__ add, int ldadd,
                         float* __restrict__ out, const float* __restrict__ bias,
                         const int* __restrict__ offs, const unsigned int* __restrict__ ep) {
    int node = blockIdx.x * 16 + (threadIdx.x >> 4);
    if (node >= NN) return;
    int f = threadIdx.x & 15;
    float acc = add[(size_t)node * ldadd + f];
    int s = offs[node], e = offs[node + 1];
    int t = s;
    for (; t + 8 <= e; t += 8) {
        unsigned int p[8];
        float v[8];
#pragma unroll
        for (int u = 0; u < 8; ++u) p[u] = ep[t + u];
#pragma unroll
        for (int u = 0; u < 8; ++u) v[u] = in[(size_t)ep_src(p[u]) * ldin + f];
#pragma unroll
        for (int u = 0; u < 8; ++u) acc = fmaf(ep_w(p[u]), v[u], acc);
    }
    for (; t < e; ++t) {
        unsigned int p0 = ep[t];
        acc = fmaf(ep_w(p0), in[(size_t)ep_src(p0) * ldin + f], acc);
    }
    if (bias) acc += bias[f];
    out[node * 16 + f] = acc;
}

// ================= MFMA bf16 GEMM — sync 2-barrier + fp8-A prefetch =================
// 128x128 tile, BK=32, 4 waves 2x2, each wave 64x64 (4x4 16x16x32 frags).
// Single-buffered LDS, compiler-scheduled. Zero-conflict swizzle + bijective XCD swizzle.
// NEW (r9): the synchronous fp8-A register load for step t+1 is issued in the
// COMPUTE region of step t (between the barriers) — its ~500-900cy latency hides
// under the MFMA phase instead of being fully exposed at the top of step t+1.
// Plain HIP only: barriers fence the load into the compute region; the compiler's
// own vmcnt placement handles the rest (no inline asm — r3/r6 lesson).
__device__ __forceinline__ void stage_bf16(char* lds, const char* src, size_t rowB,
                                           int colOff, int rowBase, int rowMax, int tid) {
    int wave = tid >> 6, lane = tid & 63;
#pragma unroll
    for (int i = 0; i < 2; ++i) {
        int L = i * 4096 + wave * 1024 + lane * 16;  // linear LDS byte offset
        int r = L >> 6;
        int kog = (L & 63) ^ (((r >> 1) & 3) << 4);  // pre-swizzled global column
        int gr = rowBase + r;
        if (gr > rowMax) gr = rowMax;
        const char* g = src + (size_t)gr * rowB + colOff + kog;
        __builtin_amdgcn_global_load_lds(
            (const __attribute__((address_space(1))) void*)g,
            (__attribute__((address_space(3))) void*)(lds + i * 4096 + wave * 1024), 16, 0, 0);
    }
}

__global__ __launch_bounds__(256) void k_gemm_mfma(
    const void* __restrict__ A0, int lda0, const void* __restrict__ A1, int lda1,
    const void* __restrict__ A2, int lda2, const void* __restrict__ A3, int lda3, int a8mask,
    const u16* __restrict__ B0, const u16* __restrict__ B1, const u16* __restrict__ B2,
    const u16* __restrict__ B3, int ldb, void* __restrict__ Cv, int ldc, int M, int Ncols,
    int Ktot, int Kq, const float* __restrict__ bias, int relu, int cmode,
    float* __restrict__ statsOut) {
    __shared__ __align__(16) char AsB[8192];
    __shared__ __align__(16) char BsB[8192];
    __shared__ float sstat[256];
    int tid = threadIdx.x;
    int wave = tid >> 6, lane = tid & 63;
    int quad = lane >> 4, lq = lane & 15;
    int wr = wave >> 1, wc = wave & 1;
    // T1 bijective XCD swizzle (m204)
    int gx = gridDim.x;
    int nwg = gx * (int)gridDim.y;
    int lin = blockIdx.y * gx + blockIdx.x;
    int xcd = lin & 7, k8 = lin >> 3;
    int q8 = nwg >> 3, r8 = nwg & 7;
    int wgid = (xcd < r8 ? xcd * (q8 + 1) : r8 * (q8 + 1) + (xcd - r8) * q8) + k8;
    int m0 = (wgid / gx) * 128, n0 = (wgid % gx) * 128;
    f32x4 acc[4][4] = {};
    if (statsOut) sstat[tid] = 0.f;

    const int NT = Ktot >> 5;
    const int spm = (Kq >> 5) - 1;  // steps-per-source mask (pow2)
    const int sps = __popc(spm);    // log2(steps per source)

    // fp8-A staging role: row r8_, 16-B half h8 (one uint4 per thread per step)
    int r8_ = tid >> 1, h8 = tid & 1;
    int gr8 = m0 + r8_;
    if (gr8 > M - 1) gr8 = M - 1;
    auto try_loadA8 = [&](int u, uint4& wv) -> bool {
        int sU = u < NT ? u : NT - 1;
        int src = sU >> sps, kk = (sU & spm) << 5;
        if (!((a8mask >> src) & 1)) return false;
        const unsigned char* A8 =
            (const unsigned char*)(src == 0 ? A0 : src == 1 ? A1 : src == 2 ? A2 : A3);
        int lda = src == 0 ? lda0 : src == 1 ? lda1 : src == 2 ? lda2 : lda3;
        wv = *(const uint4*)(A8 + (size_t)gr8 * lda + kk + h8 * 16);
        return true;
    };
    auto writeA8 = [&](uint4 wv) {
        uint4 lo, hi;
        lo.x = pkhi(__builtin_amdgcn_cvt_f32_fp8((int)wv.x, 0),
                    __builtin_amdgcn_cvt_f32_fp8((int)wv.x, 1));
        lo.y = pkhi(__builtin_amdgcn_cvt_f32_fp8((int)wv.x, 2),
                    __builtin_amdgcn_cvt_f32_fp8((int)wv.x, 3));
        lo.z = pkhi(__builtin_amdgcn_cvt_f32_fp8((int)wv.y, 0),
                    __builtin_amdgcn_cvt_f32_fp8((int)wv.y, 1));
        lo.w = pkhi(__builtin_amdgcn_cvt_f32_fp8((int)wv.y, 2),
                    __builtin_amdgcn_cvt_f32_fp8((int)wv.y, 3));
        hi.x = pkhi(__builtin_amdgcn_cvt_f32_fp8((int)wv.z, 0),
                    __builtin_amdgcn_cvt_f32_fp8((int)wv.z, 1));
        hi.y = pkhi(__builtin_amdgcn_cvt_f32_fp8((int)wv.z, 2),
                    __builtin_amdgcn_cvt_f32_fp8((int)wv.z, 3));
        hi.z = pkhi(__builtin_amdgcn_cvt_f32_fp8((int)wv.w, 0),
                    __builtin_amdgcn_cvt_f32_fp8((int)wv.w, 1));
        hi.w = pkhi(__builtin_amdgcn_cvt_f32_fp8((int)wv.w, 2),
                    __builtin_amdgcn_cvt_f32_fp8((int)wv.w, 3));
        int s = ((r8_ >> 1) & 3) << 4;
        char* dst = AsB + r8_ * 64;
        *(uint4*)(dst + ((h8 * 32) ^ s)) = lo;
        *(uint4*)(dst + ((h8 * 32 + 16) ^ s)) = hi;
    };

    uint4 pa;
    bool pa8 = try_loadA8(0, pa);  // prologue prefetch (exposed once)
    for (int t = 0; t < NT; ++t) {
        int src = t >> sps, kk = (t & spm) << 5;
        const u16* Bp = src == 0 ? B0 : src == 1 ? B1 : src == 2 ? B2 : B3;
        if (pa8) {
            writeA8(pa);  // data prefetched during step t-1's compute
        } else {
            const void* Ap = src == 0 ? A0 : src == 1 ? A1 : src == 2 ? A2 : A3;
            int lda = src == 0 ? lda0 : src == 1 ? lda1 : src == 2 ? lda2 : lda3;
            stage_bf16(AsB, (const char*)Ap, (size_t)lda * 2, kk * 2, m0, M - 1, tid);
        }
        stage_bf16(BsB, (const char*)Bp, (size_t)ldb * 2, kk * 2, n0, Ncols - 1, tid);
        __syncthreads();
        pa8 = try_loadA8(t + 1, pa);  // issue next fp8-A load; overlaps MFMA below
        bf16x8 af[4], bfr[4];
#pragma unroll
        for (int i = 0; i < 4; ++i) {
            int rr = wr * 64 + i * 16 + lq;
            af[i] = *(const bf16x8*)(AsB + rr * 64 + ((quad * 16) ^ (((rr >> 1) & 3) << 4)));
        }
#pragma unroll
        for (int j = 0; j < 4; ++j) {
            int nn2 = wc * 64 + j * 16 + lq;
            bfr[j] = *(const bf16x8*)(BsB + nn2 * 64 + ((quad * 16) ^ (((nn2 >> 1) & 3) << 4)));
        }
#pragma unroll
        for (int i = 0; i < 4; ++i)
#pragma unroll
            for (int j = 0; j < 4; ++j)
                acc[i][j] = __builtin_amdgcn_mfma_f32_16x16x32_bf16(af[i], bfr[j], acc[i][j],
                                                                    0, 0, 0);
        __syncthreads();
    }

#pragma unroll
    for (int i = 0; i < 4; ++i) {
#pragma unroll
        for (int j = 0; j < 4; ++j) {
            int jc = wc * 64 + j * 16 + lq;
            int c = n0 + jc;
            bool cok = c < Ncols;
            float bcol = (bias && cok) ? bias[c] : 0.f;
            int rbase = m0 + wr * 64 + i * 16 + quad * 4;
            float ls = 0.f, lq2 = 0.f;
#pragma unroll
            for (int reg = 0; reg < 4; ++reg) {
                int rr = rbase + reg;
                if (rr >= M || !cok) continue;
                float t = acc[i][j][reg];
                if (cmode == 2) t += b2f(*((u16*)Cv + (size_t)rr * ldc + c));
                t += bcol;
                if (relu) t = fmaxf(t, 0.f);
                if (cmode == 0)
                    ((float*)Cv)[(size_t)rr * ldc + c] = t;
                else
                    *((u16*)Cv + (size_t)rr * ldc + c) = f2b(t);
                ls += t;
                lq2 += t * t;
            }
            if (statsOut && cok) {
                atomicAdd(&sstat[jc], ls);
                atomicAdd(&sstat[128 + jc], lq2);
            }
        }
    }
    if (statsOut) {
        __syncthreads();
        if (tid < 128)
            atomicAdd(&statsOut[n0 + tid], sstat[tid]);
        else
            atomicAdd(&statsOut[512 + n0 + (tid - 128)], sstat[tid]);
    }
}

// ---------------- graphnorm apply (in place, bf16) ----------------
__global__ void k_gnorm(u16* __restrict__ X, int ld, const float* __restrict__ stats,
                        const float* __restrict__ w, const float* __restrict__ b,
                        const float* __restrict__ a) {
    int i = blockIdx.x;
    int c = threadIdx.x * 2;
    const float invn = 1.f / NN;
    ushort2 v = *(ushort2*)(X + (size_t)i * ld + c);
    float x0 = b2f(v.x), x1 = b2f(v.y);
    {
        float m = stats[c] * invn, q = stats[512 + c] * invn, al = a[c];
        float var = q - (2.f * al - al * al) * m * m;
        x0 = (x0 - al * m) * rsqrtf(var + EPSF) * w[c] + b[c];
    }
    {
        int c1 = c + 1;
        float m = stats[c1] * invn, q = stats[512 + c1] * invn, al = a[c1];
        float var = q - (2.f * al - al * al) * m * m;
        x1 = (x1 - al * m) * rsqrtf(var + EPSF) * w[c1] + b[c1];
    }
    v.x = f2b(x0);
    v.y = f2b(x1);
    *(ushort2*)(X + (size_t)i * ld + c) = v;
}

// ---- transpose weights: src (KH, I, O) fp32 -> dst (KH, O, I) bf16 ----
__global__ void k_wt(const float* __restrict__ src, u16* __restrict__ dst, int I, int O,
                     int total) {
    int idx = blockIdx.x * 256 + threadIdx.x;
    if (idx >= total) return;
    int io = I * O;
    int k = idx / io, rem = idx - k * io;
    int n = rem / I, i = rem - n * I;
    dst[idx] = f2b(src[(size_t)k * io + (size_t)i * O + n]);
}

// ---- W3 (4,512,16) fp32 -> W3T (64, 512) bf16 : W3T[k*16+f][i] = W3[k][i][f] ----
__global__ void k_wt3(const float* __restrict__ W3, u16* __restrict__ W3T) {
    int idx = blockIdx.x * 256 + threadIdx.x;
    if (idx >= 64 * 512) return;
    int n = idx >> 9, i = idx & 511;
    int k = n >> 4, f = n & 15;
    W3T[idx] = f2b(W3[((size_t)k * 512 + i) * 16 + f]);
}

extern "C" void kernel_launch(void* const* d_in, const int* in_sizes, int n_in,
                              void* d_out, int out_size, void* d_ws, size_t ws_size,
                              hipStream_t stream) {
    const float* x = (const float*)d_in[0];
    const int* ei = (const int*)d_in[1];
    const float* W1 = (const float*)d_in[2];
    const float* b1 = (const float*)d_in[3];
    const float* W2 = (const float*)d_in[4];
    const float* b2 = (const float*)d_in[5];
    const float* W3 = (const float*)d_in[6];
    const float* b3 = (const float*)d_in[7];
    const float* g1w = (const float*)d_in[8];
    const float* g1b = (const float*)d_in[9];
    const float* g1a = (const float*)d_in[10];
    const float* g2w = (const float*)d_in[11];
    const float* g2b = (const float*)d_in[12];
    const float* g2a = (const float*)d_in[13];
    const int* row = ei;
    const int* col = ei + EE;

    char* p = (char*)d_ws;
    auto alloc = [&](size_t bytes) {
        char* r = p;
        p += (bytes + 255) & ~(size_t)255;
        return r;
    };
    // Total workspace ~247.5 MB (rounds 8-13 proven budget)
    u16* H1 = (u16*)alloc((size_t)NN * 512 * 2);                  // 102.4 MB: h1 / hop fp8 park
    u16* Y = (u16*)alloc((size_t)NN * 512 * 2);                   // 102.4 MB: L1 scratch -> Y
    unsigned char* X8 = (unsigned char*)alloc((size_t)NN * 256);  // 25.6 MB fp8 width-256
    unsigned int* ep = (unsigned int*)alloc((size_t)EE * 4);      // 12.8 MB
    u16* W1T = (u16*)alloc((size_t)4 * 512 * 128 * 2);            // 0.5 MB
    u16* W2T = (u16*)alloc((size_t)4 * 512 * 512 * 2);            // 2.0 MB
    u16* W3T = (u16*)alloc(64 * 512 * 2);                         // 64 KB
    float* dinv = (float*)alloc((size_t)NN * 4);
    float* stats = (float*)alloc(2048 * 4);
    int* deg = (int*)alloc((size_t)NN * 4);
    int* offs = (int*)alloc((size_t)(NN + 1) * 4);
    int* cursor = (int*)alloc((size_t)NN * 4);
    (void)ws_size;
    (void)in_sizes;
    (void)n_in;
    (void)out_size;

    // L1 scratch parked in Y (dead before L2 GEMM1 writes Y):
    u16* xb = Y;                                                // N x 128 bf16 (25.6 MB)
    unsigned char* F8a = (unsigned char*)Y + (size_t)NN * 256;  // N x 128 fp8
    unsigned char* F8b = (unsigned char*)Y + (size_t)NN * 256 + (size_t)NN * 128;

    // ---- CSR build + weight transpose/convert
    k_init<<<cdiv(NN, 256), 256, 0, stream>>>(deg, cursor, stats);
    k_deg<<<cdiv(EE, 256), 256, 0, stream>>>(col, deg);
    k_dinv<<<cdiv(NN, 256), 256, 0, stream>>>(deg, dinv);
    k_scan<<<1, 1024, 0, stream>>>(deg, offs);
    k_scatter<<<cdiv(EE, 256), 256, 0, stream>>>(row, col, dinv, offs, cursor, ep);
    k_wt<<<cdiv(4 * 128 * 512, 256), 256, 0, stream>>>(W1, W1T, 128, 512, 4 * 128 * 512);
    k_wt<<<cdiv(4 * 512 * 512, 256), 256, 0, stream>>>(W2, W2T, 512, 512, 4 * 512 * 512);
    k_wt3<<<cdiv(64 * 512, 256), 256, 0, stream>>>(W3, W3T);

    dim3 gg(512 / 128, cdiv(NN, 128));     // (4, 782), 128x128 tiles
    const size_t WQ = (size_t)512 * 512;   // per-hop stride in W2T
    const size_t W1Q = (size_t)512 * 128;  // per-hop stride in W1T

    // ---- layer 1 (FUSED): h1 = relu(sum_{k=0..3} (A^k x) W1[k] + b1), one K=512 GEMM.
    // hop3 parks in X8 (dead until layer 2); full fp32 accumulation.
    k_cvt<<<cdiv(NN * 32, 256), 256, 0, stream>>>(x, xb, NN * 32);
    k_prop_t<0><<<NN, 64, 0, stream>>>(xb, 128, F8a, 128, offs, ep);   // hop1 fp8
    k_prop_t<1><<<NN, 64, 0, stream>>>(F8a, 128, F8b, 128, offs, ep);  // hop2 fp8
    k_prop_t<1><<<NN, 64, 0, stream>>>(F8b, 128, X8, 128, offs, ep);   // hop3 fp8 -> X8
    k_gemm_mfma<<<gg, 256, 0, stream>>>(xb, 128, F8a, 128, F8b, 128, X8, 128, 14, W1T,
                                        W1T + W1Q, W1T + 2 * W1Q, W1T + 3 * W1Q, 128, H1, 512,
                                        NN, 512, 512, 128, b1, 1, 1, stats);
    k_gnorm<<<NN, 256, 0, stream>>>(H1, 512, stats, g1w, g1b, g1a);

    // ---- layer 2: Y = relu(sum_k (A^k h1) W2[k] + b2), 2 K-chunks of width 256.
    // Chunk 0: GEMM(k=0) first (frees h1c0 slice to host hops), then K=768 hop GEMM.
    // Chunk 1 (FUSED): hops park in the now-dead h1c0 slice -> one K=1024 GEMM.
    unsigned char* hpA = (unsigned char*)H1;        // chunk-0 slice byte [0,256) per row
    unsigned char* hpB = (unsigned char*)H1 + 256;  // chunk-0 slice byte [256,512) per row
    {
        // chunk 0
        u16* h1c0 = H1;
        k_cvt8s<<<cdiv(NN * 128, 256), 256, 0, stream>>>(h1c0, 512, X8, 256);
        k_gemm_mfma<<<gg, 256, 0, stream>>>(h1c0, 512, h1c0, 512, h1c0, 512, h1c0, 512, 0,
                                            W2T, W2T, W2T, W2T, 512, Y, 512, NN, 512, 256,
                                            256, nullptr, 0, 1, nullptr);
        k_prop256<<<NN, 64, 0, stream>>>(X8, 256, hpA, 1024, offs, ep);    // hop1
        k_prop256<<<NN, 64, 0, stream>>>(hpA, 1024, hpB, 1024, offs, ep);  // hop2
        k_prop256<<<NN, 64, 0, stream>>>(hpB, 1024, X8, 256, offs, ep);    // hop3 (X8 dead)
        k_gemm_mfma<<<gg, 256, 0, stream>>>(hpA, 1024, hpB, 1024, X8, 256, X8, 256, 7,
                                            W2T + WQ, W2T + 2 * WQ, W2T + 3 * WQ, W2T, 512,
                                            Y, 512, NN, 512, 768, 256, nullptr, 0, 2,
                                            nullptr);
    }
    {
        // chunk 1 (fused): h1c1 stays alive (A0); hops reuse dead chunk-0 slice + X8
        u16* h1c1 = H1 + 256;
        k_cvt8s<<<cdiv(NN * 128, 256), 256, 0, stream>>>(h1c1, 512, X8, 256);
        k_prop256<<<NN, 64, 0, stream>>>(X8, 256, hpA, 1024, offs, ep);    // hop1
        k_prop256<<<NN, 64, 0, stream>>>(hpA, 1024, hpB, 1024, offs, ep);  // hop2
        k_prop256<<<NN, 64, 0, stream>>>(hpB, 1024, X8, 256, offs, ep);    // hop3
        k_gemm_mfma<<<gg, 256, 0, stream>>>(h1c1, 512, hpA, 1024, hpB, 1024, X8, 256, 14,
                                            W2T + 256, W2T + WQ + 256, W2T + 2 * WQ + 256,
                                            W2T + 3 * WQ + 256, 512, Y, 512, NN, 512, 1024,
                                            256, b2, 1, 2, stats + 1024);
    }
    k_gnorm<<<NN, 256, 0, stream>>>(Y, 512, stats + 1024, g2w, g2b, g2a);

    // ---- layer 3 (Horner at width 16): G = h2 @ [W3_0|W3_1|W3_2|W3_3] (fp32, H1 dead)
    float* G = (float*)H1;             // N x 64 fp32 = 25.6 MB
    float* tA = (float*)X8;            // N x 16 fp32 = 6.4 MB
    float* tB = tA + (size_t)NN * 16;  // 6.4 MB (X8 = 25.6 MB holds both)
    {
        dim3 g3(1, cdiv(NN, 128));
        k_gemm_mfma<<<g3, 256, 0, stream>>>(Y, 512, Y, 512, Y, 512, Y, 512, 0, W3T, W3T, W3T,
                                            W3T, 512, G, 64, NN, 64, 512, 512, nullptr, 0, 0,
                                            nullptr);
    }
    k_prop16<<<cdiv(NN, 16), 256, 0, stream>>>(G + 48, 64, G + 32, 64, tA, nullptr, offs, ep);
    k_prop16<<<cdiv(NN, 16), 256, 0, stream>>>(tA, 16, G + 16, 64, tB, nullptr, offs, ep);
    k_prop16<<<cdiv(NN, 16), 256, 0, stream>>>(tB, 16, G + 0, 64, (float*)d_out, b3, offs, ep);
}

// Round 10
// 2498.924 us; speedup vs baseline: 1.2025x; 1.2025x over previous
//
#include <hip/hip_runtime.h>

#define NN 100000
#define EE 3200000
#define EPSF 1e-5f

typedef unsigned short u16;
typedef short bf16x8 __attribute__((ext_vector_type(8)));
typedef float f32x4 __attribute__((ext_vector_type(4)));

static inline int cdiv(int a, int b) { return (a + b - 1) / b; }

__device__ __forceinline__ float b2f(u16 u) {
    return __uint_as_float((unsigned int)u << 16);
}
__device__ __forceinline__ u16 f2b(float f) {
    unsigned int i = __float_as_uint(f);
    return (u16)((i + 0x7FFFu + ((i >> 16) & 1u)) >> 16);  // RNE
}
// packed edge: [31:17] = positive float top bits, [16:0] = src index
__device__ __forceinline__ int ep_src(unsigned int p) { return (int)(p & 0x1FFFFu); }
__device__ __forceinline__ float ep_w(unsigned int p) {
    return __uint_as_float(p & 0xFFFE0000u);
}
// pack high16(f0) | high16(f1)<<16 — exact bf16 for values exactly representable (fp8 set)
__device__ __forceinline__ unsigned pkhi(float f0, float f1) {
    return __builtin_amdgcn_perm(__float_as_uint(f1), __float_as_uint(f0), 0x07060302u);
}

// ---------------- zero-init (graph-capture-safe) ----------------
__global__ void k_init(int* __restrict__ deg, int* __restrict__ cursor,
                       float* __restrict__ stats) {
    int i = blockIdx.x * 256 + threadIdx.x;
    if (i < NN) {
        deg[i] = 0;
        cursor[i] = 0;
    }
    if (i < 2048) stats[i] = 0.f;
}

// ---------------- degree histogram ----------------
__global__ void k_deg(const int* __restrict__ col, int* __restrict__ deg) {
    int i = blockIdx.x * 256 + threadIdx.x;
    if (i < EE) atomicAdd(&deg[col[i]], 1);
}

__global__ void k_dinv(const int* __restrict__ deg, float* __restrict__ dinv) {
    int i = blockIdx.x * 256 + threadIdx.x;
    if (i < NN) {
        int d = deg[i];
        dinv[i] = d > 0 ? rsqrtf((float)d) : 0.f;
    }
}

// ------- exclusive scan: 1024 threads, 98 contiguous elems per thread -------
__global__ void k_scan(const int* __restrict__ deg, int* __restrict__ offs) {
    __shared__ int sh[1024];
    int tid = threadIdx.x;
    int start = tid * 98;
    int end = min(start + 98, NN);
    int sum = 0;
    for (int i = start; i < end; ++i) sum += deg[i];
    sh[tid] = sum;
    __syncthreads();
    for (int off = 1; off < 1024; off <<= 1) {
        int t = (tid >= off) ? sh[tid - off] : 0;
        __syncthreads();
        sh[tid] += t;
        __syncthreads();
    }
    int base = tid ? sh[tid - 1] : 0;
    for (int i = start; i < end; ++i) {
        offs[i] = base;
        base += deg[i];
    }
    if (tid == 1023) offs[NN] = sh[1023];
}

// ---------------- CSR scatter: pack (w:15 | src:17) into one u32 ----------------
__global__ void k_scatter(const int* __restrict__ row, const int* __restrict__ col,
                          const float* __restrict__ dinv, const int* __restrict__ offs,
                          int* __restrict__ cursor, unsigned int* __restrict__ ep) {
    int i = blockIdx.x * 256 + threadIdx.x;
    if (i < EE) {
        int c = col[i], r = row[i];
        int pos = offs[c] + atomicAdd(&cursor[c], 1);
        float w = dinv[r] * dinv[c];  // >= 0
        unsigned int u = __float_as_uint(w);
        unsigned int rb = (u + 0xFFFFu + ((u >> 17) & 1u)) & 0xFFFE0000u;  // RNE @ 7-bit man
        ep[pos] = rb | (unsigned int)r;
    }
}

// ---------------- convert fp32 array -> bf16 (n4 = count of float4s) ----------------
__global__ void k_cvt(const float* __restrict__ src, u16* __restrict__ dst, int n4) {
    int idx = blockIdx.x * 256 + threadIdx.x;
    if (idx >= n4) return;
    float4 v = ((const float4*)src)[idx];
    ushort4 o;
    o.x = f2b(v.x);
    o.y = f2b(v.y);
    o.z = f2b(v.z);
    o.w = f2b(v.w);
    ((ushort4*)dst)[idx] = o;
}

// ---- convert a width-256 bf16 slice (lds_ elems) -> fp8 (ldd bytes), sequential ----
__global__ void k_cvt8s(const u16* __restrict__ src, int lds_, unsigned char* __restrict__ dst,
                        int ldd) {
    int idx = blockIdx.x * 256 + threadIdx.x;  // over NN*128 (2 elems each)
    if (idx >= NN * 128) return;
    int node = idx >> 7, f2 = (idx & 127) << 1;
    ushort2 v = *(const ushort2*)(src + (size_t)node * lds_ + f2);
    int pk = __builtin_amdgcn_cvt_pk_fp8_f32(b2f(v.x), b2f(v.y), 0, false);
    uchar2 o;
    o.x = (unsigned char)(pk & 0xFF);
    o.y = (unsigned char)((pk >> 8) & 0xFF);
    *(uchar2*)(dst + (size_t)node * ldd + f2) = o;
}

// ---- gather propagation, width 128, 64 thr/node (r7 proven config), fp8 out.
// S8: source fp8 (ldin in bytes) else bf16 (ldin in elems). ----
template <int S8>
__global__ void k_prop_t(const void* __restrict__ in, int ldin,
                         unsigned char* __restrict__ out8, int ldo8,
                         const int* __restrict__ offs, const unsigned int* __restrict__ ep) {
    int node = blockIdx.x;
    int f2 = threadIdx.x << 1;
    int s = offs[node], e = offs[node + 1];
    const u16* inb = (const u16*)in;
    const unsigned char* in8 = (const unsigned char*)in;
    float a0 = 0.f, a1 = 0.f;
    int t = s;
    for (; t + 4 <= e; t += 4) {
        unsigned int p0 = ep[t], p1 = ep[t + 1], p2 = ep[t + 2], p3 = ep[t + 3];
        float x0, y0, x1, y1, x2, y2, x3, y3;
        if (S8) {
            uchar2 c0 = *(const uchar2*)(in8 + (size_t)ep_src(p0) * ldin + f2);
            uchar2 c1 = *(const uchar2*)(in8 + (size_t)ep_src(p1) * ldin + f2);
            uchar2 c2 = *(const uchar2*)(in8 + (size_t)ep_src(p2) * ldin + f2);
            uchar2 c3 = *(const uchar2*)(in8 + (size_t)ep_src(p3) * ldin + f2);
            int w0 = c0.x | (c0.y << 8), w1 = c1.x | (c1.y << 8);
            int w2 = c2.x | (c2.y << 8), w3 = c3.x | (c3.y << 8);
            x0 = __builtin_amdgcn_cvt_f32_fp8(w0, 0);
            y0 = __builtin_amdgcn_cvt_f32_fp8(w0, 1);
            x1 = __builtin_amdgcn_cvt_f32_fp8(w1, 0);
            y1 = __builtin_amdgcn_cvt_f32_fp8(w1, 1);
            x2 = __builtin_amdgcn_cvt_f32_fp8(w2, 0);
            y2 = __builtin_amdgcn_cvt_f32_fp8(w2, 1);
            x3 = __builtin_amdgcn_cvt_f32_fp8(w3, 0);
            y3 = __builtin_amdgcn_cvt_f32_fp8(w3, 1);
        } else {
            ushort2 v0 = *(const ushort2*)(inb + (size_t)ep_src(p0) * ldin + f2);
            ushort2 v1 = *(const ushort2*)(inb + (size_t)ep_src(p1) * ldin + f2);
            ushort2 v2 = *(const ushort2*)(inb + (size_t)ep_src(p2) * ldin + f2);
            ushort2 v3 = *(const ushort2*)(inb + (size_t)ep_src(p3) * ldin + f2);
            x0 = b2f(v0.x);
            y0 = b2f(v0.y);
            x1 = b2f(v1.x);
            y1 = b2f(v1.y);
            x2 = b2f(v2.x);
            y2 = b2f(v2.y);
            x3 = b2f(v3.x);
            y3 = b2f(v3.y);
        }
        float w0 = ep_w(p0), w1 = ep_w(p1), w2 = ep_w(p2), w3 = ep_w(p3);
        a0 = fmaf(w0, x0, a0);
        a1 = fmaf(w0, y0, a1);
        a0 = fmaf(w1, x1, a0);
        a1 = fmaf(w1, y1, a1);
        a0 = fmaf(w2, x2, a0);
        a1 = fmaf(w2, y2, a1);
        a0 = fmaf(w3, x3, a0);
        a1 = fmaf(w3, y3, a1);
    }
    for (; t < e; ++t) {
        unsigned int p0 = ep[t];
        float x0, y0;
        if (S8) {
            uchar2 c0 = *(const uchar2*)(in8 + (size_t)ep_src(p0) * ldin + f2);
            int w = c0.x | (c0.y << 8);
            x0 = __builtin_amdgcn_cvt_f32_fp8(w, 0);
            y0 = __builtin_amdgcn_cvt_f32_fp8(w, 1);
        } else {
            ushort2 v0 = *(const ushort2*)(inb + (size_t)ep_src(p0) * ldin + f2);
            x0 = b2f(v0.x);
            y0 = b2f(v0.y);
        }
        float w0 = ep_w(p0);
        a0 = fmaf(w0, x0, a0);
        a1 = fmaf(w0, y0, a1);
    }
    int pk = __builtin_amdgcn_cvt_pk_fp8_f32(a0, a1, 0, false);
    uchar2 o8;
    o8.x = (unsigned char)(pk & 0xFF);
    o8.y = (unsigned char)((pk >> 8) & 0xFF);
    *(uchar2*)(out8 + (size_t)node * ldo8 + f2) = o8;
}

// ---- width-256 fp8 propagation: one wave/node, 4 cols/lane, 4x unroll (r7 proven) ----
__global__ void k_prop256(const unsigned char* __restrict__ in, int ldin,
                          unsigned char* __restrict__ out, int ldout,
                          const int* __restrict__ offs, const unsigned int* __restrict__ ep) {
    int node = blockIdx.x;
    int f4 = threadIdx.x << 2;
    int s = offs[node], e = offs[node + 1];
    float a0 = 0, a1 = 0, a2 = 0, a3 = 0;
    int t = s;
    for (; t + 4 <= e; t += 4) {
        unsigned int p[4];
        unsigned int v[4];
#pragma unroll
        for (int u = 0; u < 4; ++u) p[u] = ep[t + u];
#pragma unroll
        for (int u = 0; u < 4; ++u)
            v[u] = *(const unsigned int*)(in + (size_t)ep_src(p[u]) * ldin + f4);
#pragma unroll
        for (int u = 0; u < 4; ++u) {
            float w = ep_w(p[u]);
            a0 = fmaf(w, __builtin_amdgcn_cvt_f32_fp8((int)v[u], 0), a0);
            a1 = fmaf(w, __builtin_amdgcn_cvt_f32_fp8((int)v[u], 1), a1);
            a2 = fmaf(w, __builtin_amdgcn_cvt_f32_fp8((int)v[u], 2), a2);
            a3 = fmaf(w, __builtin_amdgcn_cvt_f32_fp8((int)v[u], 3), a3);
        }
    }
    for (; t < e; ++t) {
        unsigned int p0 = ep[t];
        unsigned int v = *(const unsigned int*)(in + (size_t)ep_src(p0) * ldin + f4);
        float w = ep_w(p0);
        a0 = fmaf(w, __builtin_amdgcn_cvt_f32_fp8((int)v, 0), a0);
        a1 = fmaf(w, __builtin_amdgcn_cvt_f32_fp8((int)v, 1), a1);
        a2 = fmaf(w, __builtin_amdgcn_cvt_f32_fp8((int)v, 2), a2);
        a3 = fmaf(w, __builtin_amdgcn_cvt_f32_fp8((int)v, 3), a3);
    }
    int p01 = __builtin_amdgcn_cvt_pk_fp8_f32(a0, a1, 0, false);
    int p23 = __builtin_amdgcn_cvt_pk_fp8_f32(a2, a3, 0, false);
    unsigned int o = (unsigned)(p01 & 0xFFFF) | ((unsigned)p23 << 16);
    *(unsigned int*)(out + (size_t)node * ldout + f4) = o;
}

// ---- width-16 fp32 propagation with addend (Horner), 16 nodes/block, 8x unroll ----
__global__ void k_prop16(const float* __restrict__ in, int ldin,
                         const float* __restrict__ add, int ldadd,
                         float* __restrict__ out, const float* __restrict__ bias,
                         const int* __restrict__ offs, const unsigned int* __restrict__ ep) {
    int node = blockIdx.x * 16 + (threadIdx.x >> 4);
    if (node >= NN) return;
    int f = threadIdx.x & 15;
    float acc = add[(size_t)node * ldadd + f];
    int s = offs[node], e = offs[node + 1];
    int t = s;
    for (; t + 8 <= e; t += 8) {
        unsigned int p[8];
        float v[8];
#pragma unroll
        for (int u = 0; u < 8; ++u) p[u] = ep[t + u];
#pragma unroll
        for (int u = 0; u < 8; ++u) v[u] = in[(size_t)ep_src(p[u]) * ldin + f];
#pragma unroll
        for (int u = 0; u < 8; ++u) acc = fmaf(ep_w(p[u]), v[u], acc);
    }
    for (; t < e; ++t) {
        unsigned int p0 = ep[t];
        acc = fmaf(ep_w(p0), in[(size_t)ep_src(p0) * ldin + f], acc);
    }
    if (bias) acc += bias[f];
    out[node * 16 + f] = acc;
}

// ================= MFMA bf16 GEMM — sync 2-barrier, 8 waves (r10) =================
// 128x128 tile, BK=32, EIGHT waves in 4x2: each wave 32x64 (2x4 16x16x32 frags).
// Halves per-thread accumulator (32 AGPR vs 64) -> higher occupancy -> more
// cross-block overlap of the per-step barrier drain (the r7 limiter: occ 30%).
// Same proven 2-barrier compiler-scheduled skeleton, zero-conflict swizzle,
// bijective XCD swizzle. Staging: exactly 16B/thread (bf16) or 8B/thread (fp8).
__device__ __forceinline__ void stage_bf16(char* lds, const char* src, size_t rowB,
                                           int colOff, int rowBase, int rowMax, int tid) {
    int L = tid << 4;  // 512 threads x 16B = 8192B
    int r = L >> 6;
    int kog = (L & 63) ^ (((r >> 1) & 3) << 4);  // pre-swizzled global column
    int gr = rowBase + r;
    if (gr > rowMax) gr = rowMax;
    const char* g = src + (size_t)gr * rowB + colOff + kog;
    __builtin_amdgcn_global_load_lds((const __attribute__((address_space(1))) void*)g,
                                     (__attribute__((address_space(3))) void*)(lds + L), 16,
                                     0, 0);
}

__global__ __launch_bounds__(512) void k_gemm_mfma(
    const void* __restrict__ A0, int lda0, const void* __restrict__ A1, int lda1,
    const void* __restrict__ A2, int lda2, const void* __restrict__ A3, int lda3, int a8mask,
    const u16* __restrict__ B0, const u16* __restrict__ B1, const u16* __restrict__ B2,
    const u16* __restrict__ B3, int ldb, void* __restrict__ Cv, int ldc, int M, int Ncols,
    int Ktot, int Kq, const float* __restrict__ bias, int relu, int cmode,
    float* __restrict__ statsOut) {
    __shared__ __align__(16) char AsB[8192];
    __shared__ __align__(16) char BsB[8192];
    __shared__ float sstat[256];
    int tid = threadIdx.x;
    int wave = tid >> 6, lane = tid & 63;
    int quad = lane >> 4, lq = lane & 15;
    int wr = wave >> 1, wc = wave & 1;  // 4x2 wave grid: 32-row x 64-col per wave
    // T1 bijective XCD swizzle (m204)
    int gx = gridDim.x;
    int nwg = gx * (int)gridDim.y;
    int lin = blockIdx.y * gx + blockIdx.x;
    int xcd = lin & 7, k8 = lin >> 3;
    int q8 = nwg >> 3, r8 = nwg & 7;
    int wgid = (xcd < r8 ? xcd * (q8 + 1) : r8 * (q8 + 1) + (xcd - r8) * q8) + k8;
    int m0 = (wgid / gx) * 128, n0 = (wgid % gx) * 128;
    f32x4 acc[2][4] = {};
    if (statsOut && tid < 256) sstat[tid] = 0.f;

    const int NT = Ktot >> 5;
    const int spm = (Kq >> 5) - 1;  // steps-per-source mask (pow2)
    const int sps = __popc(spm);    // log2(steps per source)

    for (int t = 0; t < NT; ++t) {
        int src = t >> sps, kk = (t & spm) << 5;
        const void* Ap = src == 0 ? A0 : src == 1 ? A1 : src == 2 ? A2 : A3;
        int lda = src == 0 ? lda0 : src == 1 ? lda1 : src == 2 ? lda2 : lda3;
        const u16* Bp = src == 0 ? B0 : src == 1 ? B1 : src == 2 ? B2 : B3;
        if ((a8mask >> src) & 1) {
            // fp8 A tile: 8B/thread -> cvt to bf16 -> one swizzled b128 write
            const unsigned char* A8 = (const unsigned char*)Ap;
            int r = tid >> 2, h = tid & 3;  // row r, 8-col group h
            int gr = m0 + r;
            if (gr > M - 1) gr = M - 1;
            uint2 wv = *(const uint2*)(A8 + (size_t)gr * lda + kk + h * 8);
            uint4 lo;
            lo.x = pkhi(__builtin_amdgcn_cvt_f32_fp8((int)wv.x, 0),
                        __builtin_amdgcn_cvt_f32_fp8((int)wv.x, 1));
            lo.y = pkhi(__builtin_amdgcn_cvt_f32_fp8((int)wv.x, 2),
                        __builtin_amdgcn_cvt_f32_fp8((int)wv.x, 3));
            lo.z = pkhi(__builtin_amdgcn_cvt_f32_fp8((int)wv.y, 0),
                        __builtin_amdgcn_cvt_f32_fp8((int)wv.y, 1));
            lo.w = pkhi(__builtin_amdgcn_cvt_f32_fp8((int)wv.y, 2),
                        __builtin_amdgcn_cvt_f32_fp8((int)wv.y, 3));
            int s = ((r >> 1) & 3) << 4;
            *(uint4*)(AsB + r * 64 + ((h * 16) ^ s)) = lo;
        } else {
            stage_bf16(AsB, (const char*)Ap, (size_t)lda * 2, kk * 2, m0, M - 1, tid);
        }
        stage_bf16(BsB, (const char*)Bp, (size_t)ldb * 2, kk * 2, n0, Ncols - 1, tid);
        __syncthreads();
        bf16x8 af[2], bfr[4];
#pragma unroll
        for (int i = 0; i < 2; ++i) {
            int rr = wr * 32 + i * 16 + lq;
            af[i] = *(const bf16x8*)(AsB + rr * 64 + ((quad * 16) ^ (((rr >> 1) & 3) << 4)));
        }
#pragma unroll
        for (int j = 0; j < 4; ++j) {
            int nn2 = wc * 64 + j * 16 + lq;
            bfr[j] = *(const bf16x8*)(BsB + nn2 * 64 + ((quad * 16) ^ (((nn2 >> 1) & 3) << 4)));
        }
#pragma unroll
        for (int i = 0; i < 2; ++i)
#pragma unroll
            for (int j = 0; j < 4; ++j)
                acc[i][j] = __builtin_amdgcn_mfma_f32_16x16x32_bf16(af[i], bfr[j], acc[i][j],
                                                                    0, 0, 0);
        __syncthreads();
    }

#pragma unroll
    for (int i = 0; i < 2; ++i) {
#pragma unroll
        for (int j = 0; j < 4; ++j) {
            int jc = wc * 64 + j * 16 + lq;
            int c = n0 + jc;
            bool cok = c < Ncols;
            float bcol = (bias && cok) ? bias[c] : 0.f;
            int rbase = m0 + wr * 32 + i * 16 + quad * 4;
            float ls = 0.f, lq2 = 0.f;
#pragma unroll
            for (int reg = 0; reg < 4; ++reg) {
                int rr = rbase + reg;
                if (rr >= M || !cok) continue;
                float t = acc[i][j][reg];
                if (cmode == 2) t += b2f(*((u16*)Cv + (size_t)rr * ldc + c));
                t += bcol;
                if (relu) t = fmaxf(t, 0.f);
                if (cmode == 0)
                    ((float*)Cv)[(size_t)rr * ldc + c] = t;
                else
                    *((u16*)Cv + (size_t)rr * ldc + c) = f2b(t);
                ls += t;
                lq2 += t * t;
            }
            if (statsOut && cok) {
                atomicAdd(&sstat[jc], ls);
                atomicAdd(&sstat[128 + jc], lq2);
            }
        }
    }
    if (statsOut) {
        __syncthreads();
        if (tid < 128)
            atomicAdd(&statsOut[n0 + tid], sstat[tid]);
        else if (tid < 256)
            atomicAdd(&statsOut[512 + n0 + (tid - 128)], sstat[tid]);
    }
}

// ---------------- graphnorm apply (in place, bf16) ----------------
__global__ void k_gnorm(u16* __restrict__ X, int ld, const float* __restrict__ stats,
                        const float* __restrict__ w, const float* __restrict__ b,
                        const float* __restrict__ a) {
    int i = blockIdx.x;
    int c = threadIdx.x * 2;
    const float invn = 1.f / NN;
    ushort2 v = *(ushort2*)(X + (size_t)i * ld + c);
    float x0 = b2f(v.x), x1 = b2f(v.y);
    {
        float m = stats[c] * invn, q = stats[512 + c] * invn, al = a[c];
        float var = q - (2.f * al - al * al) * m * m;
        x0 = (x0 - al * m) * rsqrtf(var + EPSF) * w[c] + b[c];
    }
    {
        int c1 = c + 1;
        float m = stats[c1] * invn, q = stats[512 + c1] * invn, al = a[c1];
        float var = q - (2.f * al - al * al) * m * m;
        x1 = (x1 - al * m) * rsqrtf(var + EPSF) * w[c1] + b[c1];
    }
    v.x = f2b(x0);
    v.y = f2b(x1);
    *(ushort2*)(X + (size_t)i * ld + c) = v;
}

// ---- transpose weights: src (KH, I, O) fp32 -> dst (KH, O, I) bf16 ----
__global__ void k_wt(const float* __restrict__ src, u16* __restrict__ dst, int I, int O,
                     int total) {
    int idx = blockIdx.x * 256 + threadIdx.x;
    if (idx >= total) return;
    int io = I * O;
    int k = idx / io, rem = idx - k * io;
    int n = rem / I, i = rem - n * I;
    dst[idx] = f2b(src[(size_t)k * io + (size_t)i * O + n]);
}

// ---- W3 (4,512,16) fp32 -> W3T (64, 512) bf16 : W3T[k*16+f][i] = W3[k][i][f] ----
__global__ void k_wt3(const float* __restrict__ W3, u16* __restrict__ W3T) {
    int idx = blockIdx.x * 256 + threadIdx.x;
    if (idx >= 64 * 512) return;
    int n = idx >> 9, i = idx & 511;
    int k = n >> 4, f = n & 15;
    W3T[idx] = f2b(W3[((size_t)k * 512 + i) * 16 + f]);
}

extern "C" void kernel_launch(void* const* d_in, const int* in_sizes, int n_in,
                              void* d_out, int out_size, void* d_ws, size_t ws_size,
                              hipStream_t stream) {
    const float* x = (const float*)d_in[0];
    const int* ei = (const int*)d_in[1];
    const float* W1 = (const float*)d_in[2];
    const float* b1 = (const float*)d_in[3];
    const float* W2 = (const float*)d_in[4];
    const float* b2 = (const float*)d_in[5];
    const float* W3 = (const float*)d_in[6];
    const float* b3 = (const float*)d_in[7];
    const float* g1w = (const float*)d_in[8];
    const float* g1b = (const float*)d_in[9];
    const float* g1a = (const float*)d_in[10];
    const float* g2w = (const float*)d_in[11];
    const float* g2b = (const float*)d_in[12];
    const float* g2a = (const float*)d_in[13];
    const int* row = ei;
    const int* col = ei + EE;

    char* p = (char*)d_ws;
    auto alloc = [&](size_t bytes) {
        char* r = p;
        p += (bytes + 255) & ~(size_t)255;
        return r;
    };
    // Total workspace ~247.5 MB (rounds 8-13 proven budget)
    u16* H1 = (u16*)alloc((size_t)NN * 512 * 2);                  // 102.4 MB: h1 / hop fp8 park
    u16* Y = (u16*)alloc((size_t)NN * 512 * 2);                   // 102.4 MB: L1 scratch -> Y
    unsigned char* X8 = (unsigned char*)alloc((size_t)NN * 256);  // 25.6 MB fp8 width-256
    unsigned int* ep = (unsigned int*)alloc((size_t)EE * 4);      // 12.8 MB
    u16* W1T = (u16*)alloc((size_t)4 * 512 * 128 * 2);            // 0.5 MB
    u16* W2T = (u16*)alloc((size_t)4 * 512 * 512 * 2);            // 2.0 MB
    u16* W3T = (u16*)alloc(64 * 512 * 2);                         // 64 KB
    float* dinv = (float*)alloc((size_t)NN * 4);
    float* stats = (float*)alloc(2048 * 4);
    int* deg = (int*)alloc((size_t)NN * 4);
    int* offs = (int*)alloc((size_t)(NN + 1) * 4);
    int* cursor = (int*)alloc((size_t)NN * 4);
    (void)ws_size;
    (void)in_sizes;
    (void)n_in;
    (void)out_size;

    // L1 scratch parked in Y (dead before L2 GEMM1 writes Y):
    u16* xb = Y;                                                // N x 128 bf16 (25.6 MB)
    unsigned char* F8a = (unsigned char*)Y + (size_t)NN * 256;  // N x 128 fp8
    unsigned char* F8b = (unsigned char*)Y + (size_t)NN * 256 + (size_t)NN * 128;

    // ---- CSR build + weight transpose/convert
    k_init<<<cdiv(NN, 256), 256, 0, stream>>>(deg, cursor, stats);
    k_deg<<<cdiv(EE, 256), 256, 0, stream>>>(col, deg);
    k_dinv<<<cdiv(NN, 256), 256, 0, stream>>>(deg, dinv);
    k_scan<<<1, 1024, 0, stream>>>(deg, offs);
    k_scatter<<<cdiv(EE, 256), 256, 0, stream>>>(row, col, dinv, offs, cursor, ep);
    k_wt<<<cdiv(4 * 128 * 512, 256), 256, 0, stream>>>(W1, W1T, 128, 512, 4 * 128 * 512);
    k_wt<<<cdiv(4 * 512 * 512, 256), 256, 0, stream>>>(W2, W2T, 512, 512, 4 * 512 * 512);
    k_wt3<<<cdiv(64 * 512, 256), 256, 0, stream>>>(W3, W3T);

    dim3 gg(512 / 128, cdiv(NN, 128));     // (4, 782), 128x128 tiles
    const size_t WQ = (size_t)512 * 512;   // per-hop stride in W2T
    const size_t W1Q = (size_t)512 * 128;  // per-hop stride in W1T

    // ---- layer 1 (FUSED): h1 = relu(sum_{k=0..3} (A^k x) W1[k] + b1), one K=512 GEMM.
    // hop3 parks in X8 (dead until layer 2); full fp32 accumulation.
    k_cvt<<<cdiv(NN * 32, 256), 256, 0, stream>>>(x, xb, NN * 32);
    k_prop_t<0><<<NN, 64, 0, stream>>>(xb, 128, F8a, 128, offs, ep);   // hop1 fp8
    k_prop_t<1><<<NN, 64, 0, stream>>>(F8a, 128, F8b, 128, offs, ep);  // hop2 fp8
    k_prop_t<1><<<NN, 64, 0, stream>>>(F8b, 128, X8, 128, offs, ep);   // hop3 fp8 -> X8
    k_gemm_mfma<<<gg, 512, 0, stream>>>(xb, 128, F8a, 128, F8b, 128, X8, 128, 14, W1T,
                                        W1T + W1Q, W1T + 2 * W1Q, W1T + 3 * W1Q, 128, H1, 512,
                                        NN, 512, 512, 128, b1, 1, 1, stats);
    k_gnorm<<<NN, 256, 0, stream>>>(H1, 512, stats, g1w, g1b, g1a);

    // ---- layer 2: Y = relu(sum_k (A^k h1) W2[k] + b2), 2 K-chunks of width 256.
    // Chunk 0: GEMM(k=0) first (frees h1c0 slice to host hops), then K=768 hop GEMM.
    // Chunk 1 (FUSED): hops park in the now-dead h1c0 slice -> one K=1024 GEMM.
    unsigned char* hpA = (unsigned char*)H1;        // chunk-0 slice byte [0,256) per row
    unsigned char* hpB = (unsigned char*)H1 + 256;  // chunk-0 slice byte [256,512) per row
    {
        // chunk 0
        u16* h1c0 = H1;
        k_cvt8s<<<cdiv(NN * 128, 256), 256, 0, stream>>>(h1c0, 512, X8, 256);
        k_gemm_mfma<<<gg, 512, 0, stream>>>(h1c0, 512, h1c0, 512, h1c0, 512, h1c0, 512, 0,
                                            W2T, W2T, W2T, W2T, 512, Y, 512, NN, 512, 256,
                                            256, nullptr, 0, 1, nullptr);
        k_prop256<<<NN, 64, 0, stream>>>(X8, 256, hpA, 1024, offs, ep);    // hop1
        k_prop256<<<NN, 64, 0, stream>>>(hpA, 1024, hpB, 1024, offs, ep);  // hop2
        k_prop256<<<NN, 64, 0, stream>>>(hpB, 1024, X8, 256, offs, ep);    // hop3 (X8 dead)
        k_gemm_mfma<<<gg, 512, 0, stream>>>(hpA, 1024, hpB, 1024, X8, 256, X8, 256, 7,
                                            W2T + WQ, W2T + 2 * WQ, W2T + 3 * WQ, W2T, 512,
                                            Y, 512, NN, 512, 768, 256, nullptr, 0, 2,
                                            nullptr);
    }
    {
        // chunk 1 (fused): h1c1 stays alive (A0); hops reuse dead chunk-0 slice + X8
        u16* h1c1 = H1 + 256;
        k_cvt8s<<<cdiv(NN * 128, 256), 256, 0, stream>>>(h1c1, 512, X8, 256);
        k_prop256<<<NN, 64, 0, stream>>>(X8, 256, hpA, 1024, offs, ep);    // hop1
        k_prop256<<<NN, 64, 0, stream>>>(hpA, 1024, hpB, 1024, offs, ep);  // hop2
        k_prop256<<<NN, 64, 0, stream>>>(hpB, 1024, X8, 256, offs, ep);    // hop3
        k_gemm_mfma<<<gg, 512, 0, stream>>>(h1c1, 512, hpA, 1024, hpB, 1024, X8, 256, 14,
                                            W2T + 256, W2T + WQ + 256, W2T + 2 * WQ + 256,
                                            W2T + 3 * WQ + 256, 512, Y, 512, NN, 512, 1024,
                                            256, b2, 1, 2, stats + 1024);
    }
    k_gnorm<<<NN, 256, 0, stream>>>(Y, 512, stats + 1024, g2w, g2b, g2a);

    // ---- layer 3 (Horner at width 16): G = h2 @ [W3_0|W3_1|W3_2|W3_3] (fp32, H1 dead)
    float* G = (float*)H1;             // N x 64 fp32 = 25.6 MB
    float* tA = (float*)X8;            // N x 16 fp32 = 6.4 MB
    float* tB = tA + (size_t)NN * 16;  // 6.4 MB (X8 = 25.6 MB holds both)
    {
        dim3 g3(1, cdiv(NN, 128));
        k_gemm_mfma<<<g3, 512, 0, stream>>>(Y, 512, Y, 512, Y, 512, Y, 512, 0, W3T, W3T, W3T,
                                            W3T, 512, G, 64, NN, 64, 512, 512, nullptr, 0, 0,
                                            nullptr);
    }
    k_prop16<<<cdiv(NN, 16), 256, 0, stream>>>(G + 48, 64, G + 32, 64, tA, nullptr, offs, ep);
    k_prop16<<<cdiv(NN, 16), 256, 0, stream>>>(tA, 16, G + 16, 64, tB, nullptr, offs, ep);
    k_prop16<<<cdiv(NN, 16), 256, 0, stream>>>(tB, 16, G + 0, 64, (float*)d_out, b3, offs, ep);
}

// Round 11
// 2466.568 us; speedup vs baseline: 1.2183x; 1.0131x over previous
//
#include <hip/hip_runtime.h>

#define NN 100000
#define EE 3200000
#define EPSF 1e-5f

typedef unsigned short u16;
typedef short bf16x8 __attribute__((ext_vector_type(8)));
typedef float f32x4 __attribute__((ext_vector_type(4)));

static inline int cdiv(int a, int b) { return (a + b - 1) / b; }

__device__ __forceinline__ float b2f(u16 u) {
    return __uint_as_float((unsigned int)u << 16);
}
__device__ __forceinline__ u16 f2b(float f) {
    unsigned int i = __float_as_uint(f);
    return (u16)((i + 0x7FFFu + ((i >> 16) & 1u)) >> 16);  // RNE
}
// packed edge: [31:17] = positive float top bits, [16:0] = src index
__device__ __forceinline__ int ep_src(unsigned int p) { return (int)(p & 0x1FFFFu); }
__device__ __forceinline__ float ep_w(unsigned int p) {
    return __uint_as_float(p & 0xFFFE0000u);
}
// pack high16(f0) | high16(f1)<<16 — exact bf16 for values exactly representable (fp8 set)
__device__ __forceinline__ unsigned pkhi(float f0, float f1) {
    return __builtin_amdgcn_perm(__float_as_uint(f1), __float_as_uint(f0), 0x07060302u);
}

// ---------------- zero-init (graph-capture-safe) ----------------
__global__ void k_init(int* __restrict__ deg, int* __restrict__ cursor,
                       float* __restrict__ stats) {
    int i = blockIdx.x * 256 + threadIdx.x;
    if (i < NN) {
        deg[i] = 0;
        cursor[i] = 0;
    }
    if (i < 2048) stats[i] = 0.f;
}

// ---------------- degree histogram ----------------
__global__ void k_deg(const int* __restrict__ col, int* __restrict__ deg) {
    int i = blockIdx.x * 256 + threadIdx.x;
    if (i < EE) atomicAdd(&deg[col[i]], 1);
}

__global__ void k_dinv(const int* __restrict__ deg, float* __restrict__ dinv) {
    int i = blockIdx.x * 256 + threadIdx.x;
    if (i < NN) {
        int d = deg[i];
        dinv[i] = d > 0 ? rsqrtf((float)d) : 0.f;
    }
}

// ------- exclusive scan: 1024 threads, 98 contiguous elems per thread -------
__global__ void k_scan(const int* __restrict__ deg, int* __restrict__ offs) {
    __shared__ int sh[1024];
    int tid = threadIdx.x;
    int start = tid * 98;
    int end = min(start + 98, NN);
    int sum = 0;
    for (int i = start; i < end; ++i) sum += deg[i];
    sh[tid] = sum;
    __syncthreads();
    for (int off = 1; off < 1024; off <<= 1) {
        int t = (tid >= off) ? sh[tid - off] : 0;
        __syncthreads();
        sh[tid] += t;
        __syncthreads();
    }
    int base = tid ? sh[tid - 1] : 0;
    for (int i = start; i < end; ++i) {
        offs[i] = base;
        base += deg[i];
    }
    if (tid == 1023) offs[NN] = sh[1023];
}

// ---------------- CSR scatter: pack (w:15 | src:17) into one u32 ----------------
__global__ void k_scatter(const int* __restrict__ row, const int* __restrict__ col,
                          const float* __restrict__ dinv, const int* __restrict__ offs,
                          int* __restrict__ cursor, unsigned int* __restrict__ ep) {
    int i = blockIdx.x * 256 + threadIdx.x;
    if (i < EE) {
        int c = col[i], r = row[i];
        int pos = offs[c] + atomicAdd(&cursor[c], 1);
        float w = dinv[r] * dinv[c];  // >= 0
        unsigned int u = __float_as_uint(w);
        unsigned int rb = (u + 0xFFFFu + ((u >> 17) & 1u)) & 0xFFFE0000u;  // RNE @ 7-bit man
        ep[pos] = rb | (unsigned int)r;
    }
}

// ---------------- convert fp32 array -> bf16 (n4 = count of float4s) ----------------
__global__ void k_cvt(const float* __restrict__ src, u16* __restrict__ dst, int n4) {
    int idx = blockIdx.x * 256 + threadIdx.x;
    if (idx >= n4) return;
    float4 v = ((const float4*)src)[idx];
    ushort4 o;
    o.x = f2b(v.x);
    o.y = f2b(v.y);
    o.z = f2b(v.z);
    o.w = f2b(v.w);
    ((ushort4*)dst)[idx] = o;
}

// ---- convert a width-256 bf16 slice (lds_ elems) -> fp8 (ldd bytes), sequential ----
__global__ void k_cvt8s(const u16* __restrict__ src, int lds_, unsigned char* __restrict__ dst,
                        int ldd) {
    int idx = blockIdx.x * 256 + threadIdx.x;  // over NN*128 (2 elems each)
    if (idx >= NN * 128) return;
    int node = idx >> 7, f2 = (idx & 127) << 1;
    ushort2 v = *(const ushort2*)(src + (size_t)node * lds_ + f2);
    int pk = __builtin_amdgcn_cvt_pk_fp8_f32(b2f(v.x), b2f(v.y), 0, false);
    uchar2 o;
    o.x = (unsigned char)(pk & 0xFF);
    o.y = (unsigned char)((pk >> 8) & 0xFF);
    *(uchar2*)(dst + (size_t)node * ldd + f2) = o;
}

// ---- gather propagation, width 128, 64 thr/node, 8x unroll (r11: deeper MLP),
// fp8 out. S8: source fp8 (ldin in bytes) else bf16 (ldin in elems). ----
template <int S8>
__global__ void k_prop_t(const void* __restrict__ in, int ldin,
                         unsigned char* __restrict__ out8, int ldo8,
                         const int* __restrict__ offs, const unsigned int* __restrict__ ep) {
    int node = blockIdx.x;
    int f2 = threadIdx.x << 1;
    int s = offs[node], e = offs[node + 1];
    const u16* inb = (const u16*)in;
    const unsigned char* in8 = (const unsigned char*)in;
    float a0 = 0.f, a1 = 0.f;
    int t = s;
    for (; t + 8 <= e; t += 8) {
        unsigned int p[8];
#pragma unroll
        for (int u = 0; u < 8; ++u) p[u] = ep[t + u];
        if (S8) {
            uchar2 c[8];
#pragma unroll
            for (int u = 0; u < 8; ++u)
                c[u] = *(const uchar2*)(in8 + (size_t)ep_src(p[u]) * ldin + f2);
#pragma unroll
            for (int u = 0; u < 8; ++u) {
                int w = c[u].x | (c[u].y << 8);
                float wt = ep_w(p[u]);
                a0 = fmaf(wt, __builtin_amdgcn_cvt_f32_fp8(w, 0), a0);
                a1 = fmaf(wt, __builtin_amdgcn_cvt_f32_fp8(w, 1), a1);
            }
        } else {
            ushort2 v[8];
#pragma unroll
            for (int u = 0; u < 8; ++u)
                v[u] = *(const ushort2*)(inb + (size_t)ep_src(p[u]) * ldin + f2);
#pragma unroll
            for (int u = 0; u < 8; ++u) {
                float wt = ep_w(p[u]);
                a0 = fmaf(wt, b2f(v[u].x), a0);
                a1 = fmaf(wt, b2f(v[u].y), a1);
            }
        }
    }
    for (; t < e; ++t) {
        unsigned int p0 = ep[t];
        float x0, y0;
        if (S8) {
            uchar2 c0 = *(const uchar2*)(in8 + (size_t)ep_src(p0) * ldin + f2);
            int w = c0.x | (c0.y << 8);
            x0 = __builtin_amdgcn_cvt_f32_fp8(w, 0);
            y0 = __builtin_amdgcn_cvt_f32_fp8(w, 1);
        } else {
            ushort2 v0 = *(const ushort2*)(inb + (size_t)ep_src(p0) * ldin + f2);
            x0 = b2f(v0.x);
            y0 = b2f(v0.y);
        }
        float w0 = ep_w(p0);
        a0 = fmaf(w0, x0, a0);
        a1 = fmaf(w0, y0, a1);
    }
    int pk = __builtin_amdgcn_cvt_pk_fp8_f32(a0, a1, 0, false);
    uchar2 o8;
    o8.x = (unsigned char)(pk & 0xFF);
    o8.y = (unsigned char)((pk >> 8) & 0xFF);
    *(uchar2*)(out8 + (size_t)node * ldo8 + f2) = o8;
}

// ---- width-256 fp8 propagation: one wave/node, 4 cols/lane, 8x unroll (r11) ----
__global__ void k_prop256(const unsigned char* __restrict__ in, int ldin,
                          unsigned char* __restrict__ out, int ldout,
                          const int* __restrict__ offs, const unsigned int* __restrict__ ep) {
    int node = blockIdx.x;
    int f4 = threadIdx.x << 2;
    int s = offs[node], e = offs[node + 1];
    float a0 = 0, a1 = 0, a2 = 0, a3 = 0;
    int t = s;
    for (; t + 8 <= e; t += 8) {
        unsigned int p[8];
        unsigned int v[8];
#pragma unroll
        for (int u = 0; u < 8; ++u) p[u] = ep[t + u];
#pragma unroll
        for (int u = 0; u < 8; ++u)
            v[u] = *(const unsigned int*)(in + (size_t)ep_src(p[u]) * ldin + f4);
#pragma unroll
        for (int u = 0; u < 8; ++u) {
            float w = ep_w(p[u]);
            a0 = fmaf(w, __builtin_amdgcn_cvt_f32_fp8((int)v[u], 0), a0);
            a1 = fmaf(w, __builtin_amdgcn_cvt_f32_fp8((int)v[u], 1), a1);
            a2 = fmaf(w, __builtin_amdgcn_cvt_f32_fp8((int)v[u], 2), a2);
            a3 = fmaf(w, __builtin_amdgcn_cvt_f32_fp8((int)v[u], 3), a3);
        }
    }
    for (; t < e; ++t) {
        unsigned int p0 = ep[t];
        unsigned int v = *(const unsigned int*)(in + (size_t)ep_src(p0) * ldin + f4);
        float w = ep_w(p0);
        a0 = fmaf(w, __builtin_amdgcn_cvt_f32_fp8((int)v, 0), a0);
        a1 = fmaf(w, __builtin_amdgcn_cvt_f32_fp8((int)v, 1), a1);
        a2 = fmaf(w, __builtin_amdgcn_cvt_f32_fp8((int)v, 2), a2);
        a3 = fmaf(w, __builtin_amdgcn_cvt_f32_fp8((int)v, 3), a3);
    }
    int p01 = __builtin_amdgcn_cvt_pk_fp8_f32(a0, a1, 0, false);
    int p23 = __builtin_amdgcn_cvt_pk_fp8_f32(a2, a3, 0, false);
    unsigned int o = (unsigned)(p01 & 0xFFFF) | ((unsigned)p23 << 16);
    *(unsigned int*)(out + (size_t)node * ldout + f4) = o;
}

// ---- width-16 fp32 propagation with addend (Horner), 16 nodes/block, 8x unroll ----
__global__ void k_prop16(const float* __restrict__ in, int ldin,
                         const float* __restrict__ add, int ldadd,
                         float* __restrict__ out, const float* __restrict__ bias,
                         const int* __restrict__ offs, const unsigned int* __restrict__ ep) {
    int node = blockIdx.x * 16 + (threadIdx.x >> 4);
    if (node >= NN) return;
    int f = threadIdx.x & 15;
    float acc = add[(size_t)node * ldadd + f];
    int s = offs[node], e = offs[node + 1];
    int t = s;
    for (; t + 8 <= e; t += 8) {
        unsigned int p[8];
        float v[8];
#pragma unroll
        for (int u = 0; u < 8; ++u) p[u] = ep[t + u];
#pragma unroll
        for (int u = 0; u < 8; ++u) v[u] = in[(size_t)ep_src(p[u]) * ldin + f];
#pragma unroll
        for (int u = 0; u < 8; ++u) acc = fmaf(ep_w(p[u]), v[u], acc);
    }
    for (; t < e; ++t) {
        unsigned int p0 = ep[t];
        acc = fmaf(ep_w(p0), in[(size_t)ep_src(p0) * ldin + f], acc);
    }
    if (bias) acc += bias[f];
    out[node * 16 + f] = acc;
}

// ================= MFMA bf16 GEMM — sync 2-barrier, 8 waves (r10 proven best) ==========
// 128x128 tile, BK=32, EIGHT waves in 4x2: each wave 32x64 (2x4 16x16x32 frags).
// Compiler-scheduled 2-barrier skeleton; zero-conflict swizzle; bijective XCD swizzle.
// GEMM pinned at ~300us by per-step drain x block-level concurrency (r7-r10 evidence);
// left untouched this round.
__device__ __forceinline__ void stage_bf16(char* lds, const char* src, size_t rowB,
                                           int colOff, int rowBase, int rowMax, int tid) {
    int L = tid << 4;  // 512 threads x 16B = 8192B
    int r = L >> 6;
    int kog = (L & 63) ^ (((r >> 1) & 3) << 4);  // pre-swizzled global column
    int gr = rowBase + r;
    if (gr > rowMax) gr = rowMax;
    const char* g = src + (size_t)gr * rowB + colOff + kog;
    __builtin_amdgcn_global_load_lds((const __attribute__((address_space(1))) void*)g,
                                     (__attribute__((address_space(3))) void*)(lds + L), 16,
                                     0, 0);
}

__global__ __launch_bounds__(512) void k_gemm_mfma(
    const void* __restrict__ A0, int lda0, const void* __restrict__ A1, int lda1,
    const void* __restrict__ A2, int lda2, const void* __restrict__ A3, int lda3, int a8mask,
    const u16* __restrict__ B0, const u16* __restrict__ B1, const u16* __restrict__ B2,
    const u16* __restrict__ B3, int ldb, void* __restrict__ Cv, int ldc, int M, int Ncols,
    int Ktot, int Kq, const float* __restrict__ bias, int relu, int cmode,
    float* __restrict__ statsOut) {
    __shared__ __align__(16) char AsB[8192];
    __shared__ __align__(16) char BsB[8192];
    __shared__ float sstat[256];
    int tid = threadIdx.x;
    int wave = tid >> 6, lane = tid & 63;
    int quad = lane >> 4, lq = lane & 15;
    int wr = wave >> 1, wc = wave & 1;  // 4x2 wave grid: 32-row x 64-col per wave
    // T1 bijective XCD swizzle (m204)
    int gx = gridDim.x;
    int nwg = gx * (int)gridDim.y;
    int lin = blockIdx.y * gx + blockIdx.x;
    int xcd = lin & 7, k8 = lin >> 3;
    int q8 = nwg >> 3, r8 = nwg & 7;
    int wgid = (xcd < r8 ? xcd * (q8 + 1) : r8 * (q8 + 1) + (xcd - r8) * q8) + k8;
    int m0 = (wgid / gx) * 128, n0 = (wgid % gx) * 128;
    f32x4 acc[2][4] = {};
    if (statsOut && tid < 256) sstat[tid] = 0.f;

    const int NT = Ktot >> 5;
    const int spm = (Kq >> 5) - 1;  // steps-per-source mask (pow2)
    const int sps = __popc(spm);    // log2(steps per source)

    for (int t = 0; t < NT; ++t) {
        int src = t >> sps, kk = (t & spm) << 5;
        const void* Ap = src == 0 ? A0 : src == 1 ? A1 : src == 2 ? A2 : A3;
        int lda = src == 0 ? lda0 : src == 1 ? lda1 : src == 2 ? lda2 : lda3;
        const u16* Bp = src == 0 ? B0 : src == 1 ? B1 : src == 2 ? B2 : B3;
        if ((a8mask >> src) & 1) {
            // fp8 A tile: 8B/thread -> cvt to bf16 -> one swizzled b128 write
            const unsigned char* A8 = (const unsigned char*)Ap;
            int r = tid >> 2, h = tid & 3;  // row r, 8-col group h
            int gr = m0 + r;
            if (gr > M - 1) gr = M - 1;
            uint2 wv = *(const uint2*)(A8 + (size_t)gr * lda + kk + h * 8);
            uint4 lo;
            lo.x = pkhi(__builtin_amdgcn_cvt_f32_fp8((int)wv.x, 0),
                        __builtin_amdgcn_cvt_f32_fp8((int)wv.x, 1));
            lo.y = pkhi(__builtin_amdgcn_cvt_f32_fp8((int)wv.x, 2),
                        __builtin_amdgcn_cvt_f32_fp8((int)wv.x, 3));
            lo.z = pkhi(__builtin_amdgcn_cvt_f32_fp8((int)wv.y, 0),
                        __builtin_amdgcn_cvt_f32_fp8((int)wv.y, 1));
            lo.w = pkhi(__builtin_amdgcn_cvt_f32_fp8((int)wv.y, 2),
                        __builtin_amdgcn_cvt_f32_fp8((int)wv.y, 3));
            int s = ((r >> 1) & 3) << 4;
            *(uint4*)(AsB + r * 64 + ((h * 16) ^ s)) = lo;
        } else {
            stage_bf16(AsB, (const char*)Ap, (size_t)lda * 2, kk * 2, m0, M - 1, tid);
        }
        stage_bf16(BsB, (const char*)Bp, (size_t)ldb * 2, kk * 2, n0, Ncols - 1, tid);
        __syncthreads();
        bf16x8 af[2], bfr[4];
#pragma unroll
        for (int i = 0; i < 2; ++i) {
            int rr = wr * 32 + i * 16 + lq;
            af[i] = *(const bf16x8*)(AsB + rr * 64 + ((quad * 16) ^ (((rr >> 1) & 3) << 4)));
        }
#pragma unroll
        for (int j = 0; j < 4; ++j) {
            int nn2 = wc * 64 + j * 16 + lq;
            bfr[j] = *(const bf16x8*)(BsB + nn2 * 64 + ((quad * 16) ^ (((nn2 >> 1) & 3) << 4)));
        }
#pragma unroll
        for (int i = 0; i < 2; ++i)
#pragma unroll
            for (int j = 0; j < 4; ++j)
                acc[i][j] = __builtin_amdgcn_mfma_f32_16x16x32_bf16(af[i], bfr[j], acc[i][j],
                                                                    0, 0, 0);
        __syncthreads();
    }

#pragma unroll
    for (int i = 0; i < 2; ++i) {
#pragma unroll
        for (int j = 0; j < 4; ++j) {
            int jc = wc * 64 + j * 16 + lq;
            int c = n0 + jc;
            bool cok = c < Ncols;
            float bcol = (bias && cok) ? bias[c] : 0.f;
            int rbase = m0 + wr * 32 + i * 16 + quad * 4;
            float ls = 0.f, lq2 = 0.f;
#pragma unroll
            for (int reg = 0; reg < 4; ++reg) {
                int rr = rbase + reg;
                if (rr >= M || !cok) continue;
                float t = acc[i][j][reg];
                if (cmode == 2) t += b2f(*((u16*)Cv + (size_t)rr * ldc + c));
                t += bcol;
                if (relu) t = fmaxf(t, 0.f);
                if (cmode == 0)
                    ((float*)Cv)[(size_t)rr * ldc + c] = t;
                else
                    *((u16*)Cv + (size_t)rr * ldc + c) = f2b(t);
                ls += t;
                lq2 += t * t;
            }
            if (statsOut && cok) {
                atomicAdd(&sstat[jc], ls);
                atomicAdd(&sstat[128 + jc], lq2);
            }
        }
    }
    if (statsOut) {
        __syncthreads();
        if (tid < 128)
            atomicAdd(&statsOut[n0 + tid], sstat[tid]);
        else if (tid < 256)
            atomicAdd(&statsOut[512 + n0 + (tid - 128)], sstat[tid]);
    }
}

// ---------------- graphnorm apply (in place, bf16) ----------------
__global__ void k_gnorm(u16* __restrict__ X, int ld, const float* __restrict__ stats,
                        const float* __restrict__ w, const float* __restrict__ b,
                        const float* __restrict__ a) {
    int i = blockIdx.x;
    int c = threadIdx.x * 2;
    const float invn = 1.f / NN;
    ushort2 v = *(ushort2*)(X + (size_t)i * ld + c);
    float x0 = b2f(v.x), x1 = b2f(v.y);
    {
        float m = stats[c] * invn, q = stats[512 + c] * invn, al = a[c];
        float var = q - (2.f * al - al * al) * m * m;
        x0 = (x0 - al * m) * rsqrtf(var + EPSF) * w[c] + b[c];
    }
    {
        int c1 = c + 1;
        float m = stats[c1] * invn, q = stats[512 + c1] * invn, al = a[c1];
        float var = q - (2.f * al - al * al) * m * m;
        x1 = (x1 - al * m) * rsqrtf(var + EPSF) * w[c1] + b[c1];
    }
    v.x = f2b(x0);
    v.y = f2b(x1);
    *(ushort2*)(X + (size_t)i * ld + c) = v;
}

// ---- transpose weights: src (KH, I, O) fp32 -> dst (KH, O, I) bf16 ----
__global__ void k_wt(const float* __restrict__ src, u16* __restrict__ dst, int I, int O,
                     int total) {
    int idx = blockIdx.x * 256 + threadIdx.x;
    if (idx >= total) return;
    int io = I * O;
    int k = idx / io, rem = idx - k * io;
    int n = rem / I, i = rem - n * I;
    dst[idx] = f2b(src[(size_t)k * io + (size_t)i * O + n]);
}

// ---- W3 (4,512,16) fp32 -> W3T (64, 512) bf16 : W3T[k*16+f][i] = W3[k][i][f] ----
__global__ void k_wt3(const float* __restrict__ W3, u16* __restrict__ W3T) {
    int idx = blockIdx.x * 256 + threadIdx.x;
    if (idx >= 64 * 512) return;
    int n = idx >> 9, i = idx & 511;
    int k = n >> 4, f = n & 15;
    W3T[idx] = f2b(W3[((size_t)k * 512 + i) * 16 + f]);
}

extern "C" void kernel_launch(void* const* d_in, const int* in_sizes, int n_in,
                              void* d_out, int out_size, void* d_ws, size_t ws_size,
                              hipStream_t stream) {
    const float* x = (const float*)d_in[0];
    const int* ei = (const int*)d_in[1];
    const float* W1 = (const float*)d_in[2];
    const float* b1 = (const float*)d_in[3];
    const float* W2 = (const float*)d_in[4];
    const float* b2 = (const float*)d_in[5];
    const float* W3 = (const float*)d_in[6];
    const float* b3 = (const float*)d_in[7];
    const float* g1w = (const float*)d_in[8];
    const float* g1b = (const float*)d_in[9];
    const float* g1a = (const float*)d_in[10];
    const float* g2w = (const float*)d_in[11];
    const float* g2b = (const float*)d_in[12];
    const float* g2a = (const float*)d_in[13];
    const int* row = ei;
    const int* col = ei + EE;

    char* p = (char*)d_ws;
    auto alloc = [&](size_t bytes) {
        char* r = p;
        p += (bytes + 255) & ~(size_t)255;
        return r;
    };
    // Total workspace ~247.5 MB (rounds 8-13 proven budget)
    u16* H1 = (u16*)alloc((size_t)NN * 512 * 2);                  // 102.4 MB: h1 / hop fp8 park
    u16* Y = (u16*)alloc((size_t)NN * 512 * 2);                   // 102.4 MB: L1 scratch -> Y
    unsigned char* X8 = (unsigned char*)alloc((size_t)NN * 256);  // 25.6 MB fp8 width-256
    unsigned int* ep = (unsigned int*)alloc((size_t)EE * 4);      // 12.8 MB
    u16* W1T = (u16*)alloc((size_t)4 * 512 * 128 * 2);            // 0.5 MB
    u16* W2T = (u16*)alloc((size_t)4 * 512 * 512 * 2);            // 2.0 MB
    u16* W3T = (u16*)alloc(64 * 512 * 2);                         // 64 KB
    float* dinv = (float*)alloc((size_t)NN * 4);
    float* stats = (float*)alloc(2048 * 4);
    int* deg = (int*)alloc((size_t)NN * 4);
    int* offs = (int*)alloc((size_t)(NN + 1) * 4);
    int* cursor = (int*)alloc((size_t)NN * 4);
    (void)ws_size;
    (void)in_sizes;
    (void)n_in;
    (void)out_size;

    // L1 scratch parked in Y (dead before L2 GEMM1 writes Y):
    u16* xb = Y;                                                // N x 128 bf16 (25.6 MB)
    unsigned char* F8a = (unsigned char*)Y + (size_t)NN * 256;  // N x 128 fp8
    unsigned char* F8b = (unsigned char*)Y + (size_t)NN * 256 + (size_t)NN * 128;

    // ---- CSR build + weight transpose/convert
    k_init<<<cdiv(NN, 256), 256, 0, stream>>>(deg, cursor, stats);
    k_deg<<<cdiv(EE, 256), 256, 0, stream>>>(col, deg);
    k_dinv<<<cdiv(NN, 256), 256, 0, stream>>>(deg, dinv);
    k_scan<<<1, 1024, 0, stream>>>(deg, offs);
    k_scatter<<<cdiv(EE, 256), 256, 0, stream>>>(row, col, dinv, offs, cursor, ep);
    k_wt<<<cdiv(4 * 128 * 512, 256), 256, 0, stream>>>(W1, W1T, 128, 512, 4 * 128 * 512);
    k_wt<<<cdiv(4 * 512 * 512, 256), 256, 0, stream>>>(W2, W2T, 512, 512, 4 * 512 * 512);
    k_wt3<<<cdiv(64 * 512, 256), 256, 0, stream>>>(W3, W3T);

    dim3 gg(512 / 128, cdiv(NN, 128));     // (4, 782), 128x128 tiles
    const size_t WQ = (size_t)512 * 512;   // per-hop stride in W2T
    const size_t W1Q = (size_t)512 * 128;  // per-hop stride in W1T

    // ---- layer 1 (FUSED): h1 = relu(sum_{k=0..3} (A^k x) W1[k] + b1), one K=512 GEMM.
    // hop3 parks in X8 (dead until layer 2); full fp32 accumulation.
    k_cvt<<<cdiv(NN * 32, 256), 256, 0, stream>>>(x, xb, NN * 32);
    k_prop_t<0><<<NN, 64, 0, stream>>>(xb, 128, F8a, 128, offs, ep);   // hop1 fp8
    k_prop_t<1><<<NN, 64, 0, stream>>>(F8a, 128, F8b, 128, offs, ep);  // hop2 fp8
    k_prop_t<1><<<NN, 64, 0, stream>>>(F8b, 128, X8, 128, offs, ep);   // hop3 fp8 -> X8
    k_gemm_mfma<<<gg, 512, 0, stream>>>(xb, 128, F8a, 128, F8b, 128, X8, 128, 14, W1T,
                                        W1T + W1Q, W1T + 2 * W1Q, W1T + 3 * W1Q, 128, H1, 512,
                                        NN, 512, 512, 128, b1, 1, 1, stats);
    k_gnorm<<<NN, 256, 0, stream>>>(H1, 512, stats, g1w, g1b, g1a);

    // ---- layer 2: Y = relu(sum_k (A^k h1) W2[k] + b2), 2 K-chunks of width 256.
    // Chunk 0: GEMM(k=0) first (frees h1c0 slice to host hops), then K=768 hop GEMM.
    // Chunk 1 (FUSED): hops park in the now-dead h1c0 slice -> one K=1024 GEMM.
    unsigned char* hpA = (unsigned char*)H1;        // chunk-0 slice byte [0,256) per row
    unsigned char* hpB = (unsigned char*)H1 + 256;  // chunk-0 slice byte [256,512) per row
    {
        // chunk 0
        u16* h1c0 = H1;
        k_cvt8s<<<cdiv(NN * 128, 256), 256, 0, stream>>>(h1c0, 512, X8, 256);
        k_gemm_mfma<<<gg, 512, 0, stream>>>(h1c0, 512, h1c0, 512, h1c0, 512, h1c0, 512, 0,
                                            W2T, W2T, W2T, W2T, 512, Y, 512, NN, 512, 256,
                                            256, nullptr, 0, 1, nullptr);
        k_prop256<<<NN, 64, 0, stream>>>(X8, 256, hpA, 1024, offs, ep);    // hop1
        k_prop256<<<NN, 64, 0, stream>>>(hpA, 1024, hpB, 1024, offs, ep);  // hop2
        k_prop256<<<NN, 64, 0, stream>>>(hpB, 1024, X8, 256, offs, ep);    // hop3 (X8 dead)
        k_gemm_mfma<<<gg, 512, 0, stream>>>(hpA, 1024, hpB, 1024, X8, 256, X8, 256, 7,
                                            W2T + WQ, W2T + 2 * WQ, W2T + 3 * WQ, W2T, 512,
                                            Y, 512, NN, 512, 768, 256, nullptr, 0, 2,
                                            nullptr);
    }
    {
        // chunk 1 (fused): h1c1 stays alive (A0); hops reuse dead chunk-0 slice + X8
        u16* h1c1 = H1 + 256;
        k_cvt8s<<<cdiv(NN * 128, 256), 256, 0, stream>>>(h1c1, 512, X8, 256);
        k_prop256<<<NN, 64, 0, stream>>>(X8, 256, hpA, 1024, offs, ep);    // hop1
        k_prop256<<<NN, 64, 0, stream>>>(hpA, 1024, hpB, 1024, offs, ep);  // hop2
        k_prop256<<<NN, 64, 0, stream>>>(hpB, 1024, X8, 256, offs, ep);    // hop3
        k_gemm_mfma<<<gg, 512, 0, stream>>>(h1c1, 512, hpA, 1024, hpB, 1024, X8, 256, 14,
                                            W2T + 256, W2T + WQ + 256, W2T + 2 * WQ + 256,
                                            W2T + 3 * WQ + 256, 512, Y, 512, NN, 512, 1024,
                                            256, b2, 1, 2, stats + 1024);
    }
    k_gnorm<<<NN, 256, 0, stream>>>(Y, 512, stats + 1024, g2w, g2b, g2a);

    // ---- layer 3 (Horner at width 16): G = h2 @ [W3_0|W3_1|W3_2|W3_3] (fp32, H1 dead)
    float* G = (float*)H1;             // N x 64 fp32 = 25.6 MB
    float* tA = (float*)X8;            // N x 16 fp32 = 6.4 MB
    float* tB = tA + (size_t)NN * 16;  // 6.4 MB (X8 = 25.6 MB holds both)
    {
        dim3 g3(1, cdiv(NN, 128));
        k_gemm_mfma<<<g3, 512, 0, stream>>>(Y, 512, Y, 512, Y, 512, Y, 512, 0, W3T, W3T, W3T,
                                            W3T, 512, G, 64, NN, 64, 512, 512, nullptr, 0, 0,
                                            nullptr);
    }
    k_prop16<<<cdiv(NN, 16), 256, 0, stream>>>(G + 48, 64, G + 32, 64, tA, nullptr, offs, ep);
    k_prop16<<<cdiv(NN, 16), 256, 0, stream>>>(tA, 16, G + 16, 64, tB, nullptr, offs, ep);
    k_prop16<<<cdiv(NN, 16), 256, 0, stream>>>(tB, 16, G + 0, 64, (float*)d_out, b3, offs, ep);
}

// Round 12
// 2458.732 us; speedup vs baseline: 1.2221x; 1.0032x over previous
//
#include <hip/hip_runtime.h>

#define NN 100000
#define EE 3200000
#define EPSF 1e-5f

typedef unsigned short u16;
typedef short bf16x8 __attribute__((ext_vector_type(8)));
typedef float f32x4 __attribute__((ext_vector_type(4)));

static inline int cdiv(int a, int b) { return (a + b - 1) / b; }

__device__ __forceinline__ float b2f(u16 u) {
    return __uint_as_float((unsigned int)u << 16);
}
__device__ __forceinline__ u16 f2b(float f) {
    unsigned int i = __float_as_uint(f);
    return (u16)((i + 0x7FFFu + ((i >> 16) & 1u)) >> 16);  // RNE
}
// packed edge: [31:17] = positive float top bits, [16:0] = src index
__device__ __forceinline__ int ep_src(unsigned int p) { return (int)(p & 0x1FFFFu); }
__device__ __forceinline__ float ep_w(unsigned int p) {
    return __uint_as_float(p & 0xFFFE0000u);
}
// pack high16(f0) | high16(f1)<<16 — exact bf16 for values exactly representable (fp8 set)
__device__ __forceinline__ unsigned pkhi(float f0, float f1) {
    return __builtin_amdgcn_perm(__float_as_uint(f1), __float_as_uint(f0), 0x07060302u);
}

// ---------------- zero-init (graph-capture-safe) ----------------
__global__ void k_init(int* __restrict__ deg, int* __restrict__ cursor,
                       float* __restrict__ stats) {
    int i = blockIdx.x * 256 + threadIdx.x;
    if (i < NN) {
        deg[i] = 0;
        cursor[i] = 0;
    }
    if (i < 2048) stats[i] = 0.f;
}

// ---------------- degree histogram ----------------
__global__ void k_deg(const int* __restrict__ col, int* __restrict__ deg) {
    int i = blockIdx.x * 256 + threadIdx.x;
    if (i < EE) atomicAdd(&deg[col[i]], 1);
}

__global__ void k_dinv(const int* __restrict__ deg, float* __restrict__ dinv) {
    int i = blockIdx.x * 256 + threadIdx.x;
    if (i < NN) {
        int d = deg[i];
        dinv[i] = d > 0 ? rsqrtf((float)d) : 0.f;
    }
}

// ------- exclusive scan: 1024 threads, 98 contiguous elems per thread -------
__global__ void k_scan(const int* __restrict__ deg, int* __restrict__ offs) {
    __shared__ int sh[1024];
    int tid = threadIdx.x;
    int start = tid * 98;
    int end = min(start + 98, NN);
    int sum = 0;
    for (int i = start; i < end; ++i) sum += deg[i];
    sh[tid] = sum;
    __syncthreads();
    for (int off = 1; off < 1024; off <<= 1) {
        int t = (tid >= off) ? sh[tid - off] : 0;
        __syncthreads();
        sh[tid] += t;
        __syncthreads();
    }
    int base = tid ? sh[tid - 1] : 0;
    for (int i = start; i < end; ++i) {
        offs[i] = base;
        base += deg[i];
    }
    if (tid == 1023) offs[NN] = sh[1023];
}

// ---------------- CSR scatter: pack (w:15 | src:17) into one u32 ----------------
__global__ void k_scatter(const int* __restrict__ row, const int* __restrict__ col,
                          const float* __restrict__ dinv, const int* __restrict__ offs,
                          int* __restrict__ cursor, unsigned int* __restrict__ ep) {
    int i = blockIdx.x * 256 + threadIdx.x;
    if (i < EE) {
        int c = col[i], r = row[i];
        int pos = offs[c] + atomicAdd(&cursor[c], 1);
        float w = dinv[r] * dinv[c];  // >= 0
        unsigned int u = __float_as_uint(w);
        unsigned int rb = (u + 0xFFFFu + ((u >> 17) & 1u)) & 0xFFFE0000u;  // RNE @ 7-bit man
        ep[pos] = rb | (unsigned int)r;
    }
}

// ---------------- convert fp32 array -> bf16 (n4 = count of float4s) ----------------
__global__ void k_cvt(const float* __restrict__ src, u16* __restrict__ dst, int n4) {
    int idx = blockIdx.x * 256 + threadIdx.x;
    if (idx >= n4) return;
    float4 v = ((const float4*)src)[idx];
    ushort4 o;
    o.x = f2b(v.x);
    o.y = f2b(v.y);
    o.z = f2b(v.z);
    o.w = f2b(v.w);
    ((ushort4*)dst)[idx] = o;
}

// ---- convert a width-256 bf16 slice (lds_ elems) -> fp8 (ldd bytes), sequential ----
__global__ void k_cvt8s(const u16* __restrict__ src, int lds_, unsigned char* __restrict__ dst,
                        int ldd) {
    int idx = blockIdx.x * 256 + threadIdx.x;  // over NN*128 (2 elems each)
    if (idx >= NN * 128) return;
    int node = idx >> 7, f2 = (idx & 127) << 1;
    ushort2 v = *(const ushort2*)(src + (size_t)node * lds_ + f2);
    int pk = __builtin_amdgcn_cvt_pk_fp8_f32(b2f(v.x), b2f(v.y), 0, false);
    uchar2 o;
    o.x = (unsigned char)(pk & 0xFF);
    o.y = (unsigned char)((pk >> 8) & 0xFF);
    *(uchar2*)(dst + (size_t)node * ldd + f2) = o;
}

// ---- gather propagation, width 128, 64 thr/node, 8x unroll, fp8 out.
// S8: source fp8 (ldin in bytes) else bf16 (ldin in elems). ----
template <int S8>
__global__ void k_prop_t(const void* __restrict__ in, int ldin,
                         unsigned char* __restrict__ out8, int ldo8,
                         const int* __restrict__ offs, const unsigned int* __restrict__ ep) {
    int node = blockIdx.x;
    int f2 = threadIdx.x << 1;
    int s = offs[node], e = offs[node + 1];
    const u16* inb = (const u16*)in;
    const unsigned char* in8 = (const unsigned char*)in;
    float a0 = 0.f, a1 = 0.f;
    int t = s;
    for (; t + 8 <= e; t += 8) {
        unsigned int p[8];
#pragma unroll
        for (int u = 0; u < 8; ++u) p[u] = ep[t + u];
        if (S8) {
            uchar2 c[8];
#pragma unroll
            for (int u = 0; u < 8; ++u)
                c[u] = *(const uchar2*)(in8 + (size_t)ep_src(p[u]) * ldin + f2);
#pragma unroll
            for (int u = 0; u < 8; ++u) {
                int w = c[u].x | (c[u].y << 8);
                float wt = ep_w(p[u]);
                a0 = fmaf(wt, __builtin_amdgcn_cvt_f32_fp8(w, 0), a0);
                a1 = fmaf(wt, __builtin_amdgcn_cvt_f32_fp8(w, 1), a1);
            }
        } else {
            ushort2 v[8];
#pragma unroll
            for (int u = 0; u < 8; ++u)
                v[u] = *(const ushort2*)(inb + (size_t)ep_src(p[u]) * ldin + f2);
#pragma unroll
            for (int u = 0; u < 8; ++u) {
                float wt = ep_w(p[u]);
                a0 = fmaf(wt, b2f(v[u].x), a0);
                a1 = fmaf(wt, b2f(v[u].y), a1);
            }
        }
    }
    for (; t < e; ++t) {
        unsigned int p0 = ep[t];
        float x0, y0;
        if (S8) {
            uchar2 c0 = *(const uchar2*)(in8 + (size_t)ep_src(p0) * ldin + f2);
            int w = c0.x | (c0.y << 8);
            x0 = __builtin_amdgcn_cvt_f32_fp8(w, 0);
            y0 = __builtin_amdgcn_cvt_f32_fp8(w, 1);
        } else {
            ushort2 v0 = *(const ushort2*)(inb + (size_t)ep_src(p0) * ldin + f2);
            x0 = b2f(v0.x);
            y0 = b2f(v0.y);
        }
        float w0 = ep_w(p0);
        a0 = fmaf(w0, x0, a0);
        a1 = fmaf(w0, y0, a1);
    }
    int pk = __builtin_amdgcn_cvt_pk_fp8_f32(a0, a1, 0, false);
    uchar2 o8;
    o8.x = (unsigned char)(pk & 0xFF);
    o8.y = (unsigned char)((pk >> 8) & 0xFF);
    *(uchar2*)(out8 + (size_t)node * ldo8 + f2) = o8;
}

// ---- width-256 fp8 propagation: one wave/node, 4 cols/lane, 8x unroll ----
__global__ void k_prop256(const unsigned char* __restrict__ in, int ldin,
                          unsigned char* __restrict__ out, int ldout,
                          const int* __restrict__ offs, const unsigned int* __restrict__ ep) {
    int node = blockIdx.x;
    int f4 = threadIdx.x << 2;
    int s = offs[node], e = offs[node + 1];
    float a0 = 0, a1 = 0, a2 = 0, a3 = 0;
    int t = s;
    for (; t + 8 <= e; t += 8) {
        unsigned int p[8];
        unsigned int v[8];
#pragma unroll
        for (int u = 0; u < 8; ++u) p[u] = ep[t + u];
#pragma unroll
        for (int u = 0; u < 8; ++u)
            v[u] = *(const unsigned int*)(in + (size_t)ep_src(p[u]) * ldin + f4);
#pragma unroll
        for (int u = 0; u < 8; ++u) {
            float w = ep_w(p[u]);
            a0 = fmaf(w, __builtin_amdgcn_cvt_f32_fp8((int)v[u], 0), a0);
            a1 = fmaf(w, __builtin_amdgcn_cvt_f32_fp8((int)v[u], 1), a1);
            a2 = fmaf(w, __builtin_amdgcn_cvt_f32_fp8((int)v[u], 2), a2);
            a3 = fmaf(w, __builtin_amdgcn_cvt_f32_fp8((int)v[u], 3), a3);
        }
    }
    for (; t < e; ++t) {
        unsigned int p0 = ep[t];
        unsigned int v = *(const unsigned int*)(in + (size_t)ep_src(p0) * ldin + f4);
        float w = ep_w(p0);
        a0 = fmaf(w, __builtin_amdgcn_cvt_f32_fp8((int)v, 0), a0);
        a1 = fmaf(w, __builtin_amdgcn_cvt_f32_fp8((int)v, 1), a1);
        a2 = fmaf(w, __builtin_amdgcn_cvt_f32_fp8((int)v, 2), a2);
        a3 = fmaf(w, __builtin_amdgcn_cvt_f32_fp8((int)v, 3), a3);
    }
    int p01 = __builtin_amdgcn_cvt_pk_fp8_f32(a0, a1, 0, false);
    int p23 = __builtin_amdgcn_cvt_pk_fp8_f32(a2, a3, 0, false);
    unsigned int o = (unsigned)(p01 & 0xFFFF) | ((unsigned)p23 << 16);
    *(unsigned int*)(out + (size_t)node * ldout + f4) = o;
}

// ---- width-16 fp32 propagation with addend (Horner), 16 nodes/block, 8x unroll ----
__global__ void k_prop16(const float* __restrict__ in, int ldin,
                         const float* __restrict__ add, int ldadd,
                         float* __restrict__ out, const float* __restrict__ bias,
                         const int* __restrict__ offs, const unsigned int* __restrict__ ep) {
    int node = blockIdx.x * 16 + (threadIdx.x >> 4);
    if (node >= NN) return;
    int f = threadIdx.x & 15;
    float acc = add[(size_t)node * ldadd + f];
    int s = offs[node], e = offs[node + 1];
    int t = s;
    for (; t + 8 <= e; t += 8) {
        unsigned int p[8];
        float v[8];
#pragma unroll
        for (int u = 0; u < 8; ++u) p[u] = ep[t + u];
#pragma unroll
        for (int u = 0; u < 8; ++u) v[u] = in[(size_t)ep_src(p[u]) * ldin + f];
#pragma unroll
        for (int u = 0; u < 8; ++u) acc = fmaf(ep_w(p[u]), v[u], acc);
    }
    for (; t < e; ++t) {
        unsigned int p0 = ep[t];
        acc = fmaf(ep_w(p0), in[(size_t)ep_src(p0) * ldin + f], acc);
    }
    if (bias) acc += bias[f];
    out[node * 16 + f] = acc;
}

// ================= MFMA bf16 GEMM — sync 2-barrier, 8 waves, BK=64 (r12) =============
// 128x128 tile, BK=64 organized as TWO independent BK=32 panels; each panel keeps the
// r10-proven conflict-free layout (64-B rows, ((r>>1)&3)<<4 swizzle, linear
// global_load_lds with pre-swizzled source, r10 fp8 reg-stage mapping). One barrier
// pair now covers 2 panels -> 16 MFMA/wave/step -> HALF the per-step drains (the
// r7-r11 measured limiter: ~4600cy/step vs ~80cy MFMA). No sync-structure change.
__device__ __forceinline__ void stage_bf16(char* lds, const char* src, size_t rowB,
                                           int colOff, int rowBase, int rowMax, int tid) {
    int L = tid << 4;  // 512 threads x 16B = 8192B panel
    int r = L >> 6;
    int kog = (L & 63) ^ (((r >> 1) & 3) << 4);  // pre-swizzled global column
    int gr = rowBase + r;
    if (gr > rowMax) gr = rowMax;
    const char* g = src + (size_t)gr * rowB + colOff + kog;
    __builtin_amdgcn_global_load_lds((const __attribute__((address_space(1))) void*)g,
                                     (__attribute__((address_space(3))) void*)(lds + L), 16,
                                     0, 0);
}

__global__ __launch_bounds__(512) void k_gemm_mfma(
    const void* __restrict__ A0, int lda0, const void* __restrict__ A1, int lda1,
    const void* __restrict__ A2, int lda2, const void* __restrict__ A3, int lda3, int a8mask,
    const u16* __restrict__ B0, const u16* __restrict__ B1, const u16* __restrict__ B2,
    const u16* __restrict__ B3, int ldb, void* __restrict__ Cv, int ldc, int M, int Ncols,
    int Ktot, int Kq, const float* __restrict__ bias, int relu, int cmode,
    float* __restrict__ statsOut) {
    __shared__ __align__(16) char AsB[2][8192];
    __shared__ __align__(16) char BsB[2][8192];
    __shared__ float sstat[256];
    int tid = threadIdx.x;
    int wave = tid >> 6, lane = tid & 63;
    int quad = lane >> 4, lq = lane & 15;
    int wr = wave >> 1, wc = wave & 1;  // 4x2 wave grid: 32-row x 64-col per wave
    // T1 bijective XCD swizzle (m204)
    int gx = gridDim.x;
    int nwg = gx * (int)gridDim.y;
    int lin = blockIdx.y * gx + blockIdx.x;
    int xcd = lin & 7, k8 = lin >> 3;
    int q8 = nwg >> 3, r8 = nwg & 7;
    int wgid = (xcd < r8 ? xcd * (q8 + 1) : r8 * (q8 + 1) + (xcd - r8) * q8) + k8;
    int m0 = (wgid / gx) * 128, n0 = (wgid % gx) * 128;
    f32x4 acc[2][4] = {};
    if (statsOut && tid < 256) sstat[tid] = 0.f;

    const int NT = Ktot >> 5;       // 32-wide sub-steps; always even (K mult of 64)
    const int spm = (Kq >> 5) - 1;  // sub-steps-per-source mask (pow2)
    const int sps = __popc(spm);    // log2(sub-steps per source)

    for (int t = 0; t < NT; t += 2) {
#pragma unroll
        for (int half = 0; half < 2; ++half) {
            int tt = t + half;
            int src = tt >> sps, kk = (tt & spm) << 5;
            const void* Ap = src == 0 ? A0 : src == 1 ? A1 : src == 2 ? A2 : A3;
            int lda = src == 0 ? lda0 : src == 1 ? lda1 : src == 2 ? lda2 : lda3;
            const u16* Bp = src == 0 ? B0 : src == 1 ? B1 : src == 2 ? B2 : B3;
            if ((a8mask >> src) & 1) {
                // fp8 A panel: 8B/thread -> cvt to bf16 -> one swizzled b128 write
                const unsigned char* A8 = (const unsigned char*)Ap;
                int r = tid >> 2, h = tid & 3;  // row r, 8-col group h
                int gr = m0 + r;
                if (gr > M - 1) gr = M - 1;
                uint2 wv = *(const uint2*)(A8 + (size_t)gr * lda + kk + h * 8);
                uint4 lo;
                lo.x = pkhi(__builtin_amdgcn_cvt_f32_fp8((int)wv.x, 0),
                            __builtin_amdgcn_cvt_f32_fp8((int)wv.x, 1));
                lo.y = pkhi(__builtin_amdgcn_cvt_f32_fp8((int)wv.x, 2),
                            __builtin_amdgcn_cvt_f32_fp8((int)wv.x, 3));
                lo.z = pkhi(__builtin_amdgcn_cvt_f32_fp8((int)wv.y, 0),
                            __builtin_amdgcn_cvt_f32_fp8((int)wv.y, 1));
                lo.w = pkhi(__builtin_amdgcn_cvt_f32_fp8((int)wv.y, 2),
                            __builtin_amdgcn_cvt_f32_fp8((int)wv.y, 3));
                int s = ((r >> 1) & 3) << 4;
                *(uint4*)(AsB[half] + r * 64 + ((h * 16) ^ s)) = lo;
            } else {
                stage_bf16(AsB[half], (const char*)Ap, (size_t)lda * 2, kk * 2, m0, M - 1,
                           tid);
            }
            stage_bf16(BsB[half], (const char*)Bp, (size_t)ldb * 2, kk * 2, n0, Ncols - 1,
                       tid);
        }
        __syncthreads();
#pragma unroll
        for (int kh = 0; kh < 2; ++kh) {
            bf16x8 af[2], bfr[4];
#pragma unroll
            for (int i = 0; i < 2; ++i) {
                int rr = wr * 32 + i * 16 + lq;
                af[i] = *(const bf16x8*)(AsB[kh] + rr * 64 +
                                         ((quad * 16) ^ (((rr >> 1) & 3) << 4)));
            }
#pragma unroll
            for (int j = 0; j < 4; ++j) {
                int nn2 = wc * 64 + j * 16 + lq;
                bfr[j] = *(const bf16x8*)(BsB[kh] + nn2 * 64 +
                                          ((quad * 16) ^ (((nn2 >> 1) & 3) << 4)));
            }
#pragma unroll
            for (int i = 0; i < 2; ++i)
#pragma unroll
                for (int j = 0; j < 4; ++j)
                    acc[i][j] = __builtin_amdgcn_mfma_f32_16x16x32_bf16(af[i], bfr[j],
                                                                        acc[i][j], 0, 0, 0);
        }
        __syncthreads();
    }

#pragma unroll
    for (int i = 0; i < 2; ++i) {
#pragma unroll
        for (int j = 0; j < 4; ++j) {
            int jc = wc * 64 + j * 16 + lq;
            int c = n0 + jc;
            bool cok = c < Ncols;
            float bcol = (bias && cok) ? bias[c] : 0.f;
            int rbase = m0 + wr * 32 + i * 16 + quad * 4;
            float ls = 0.f, lq2 = 0.f;
#pragma unroll
            for (int reg = 0; reg < 4; ++reg) {
                int rr = rbase + reg;
                if (rr >= M || !cok) continue;
                float t = acc[i][j][reg];
                if (cmode == 2) t += b2f(*((u16*)Cv + (size_t)rr * ldc + c));
                t += bcol;
                if (relu) t = fmaxf(t, 0.f);
                if (cmode == 0)
                    ((float*)Cv)[(size_t)rr * ldc + c] = t;
                else
                    *((u16*)Cv + (size_t)rr * ldc + c) = f2b(t);
                ls += t;
                lq2 += t * t;
            }
            if (statsOut && cok) {
                atomicAdd(&sstat[jc], ls);
                atomicAdd(&sstat[128 + jc], lq2);
            }
        }
    }
    if (statsOut) {
        __syncthreads();
        if (tid < 128)
            atomicAdd(&statsOut[n0 + tid], sstat[tid]);
        else if (tid < 256)
            atomicAdd(&statsOut[512 + n0 + (tid - 128)], sstat[tid]);
    }
}

// ---------------- graphnorm apply (in place, bf16) ----------------
__global__ void k_gnorm(u16* __restrict__ X, int ld, const float* __restrict__ stats,
                        const float* __restrict__ w, const float* __restrict__ b,
                        const float* __restrict__ a) {
    int i = blockIdx.x;
    int c = threadIdx.x * 2;
    const float invn = 1.f / NN;
    ushort2 v = *(ushort2*)(X + (size_t)i * ld + c);
    float x0 = b2f(v.x), x1 = b2f(v.y);
    {
        float m = stats[c] * invn, q = stats[512 + c] * invn, al = a[c];
        float var = q - (2.f * al - al * al) * m * m;
        x0 = (x0 - al * m) * rsqrtf(var + EPSF) * w[c] + b[c];
    }
    {
        int c1 = c + 1;
        float m = stats[c1] * invn, q = stats[512 + c1] * invn, al = a[c1];
        float var = q - (2.f * al - al * al) * m * m;
        x1 = (x1 - al * m) * rsqrtf(var + EPSF) * w[c1] + b[c1];
    }
    v.x = f2b(x0);
    v.y = f2b(x1);
    *(ushort2*)(X + (size_t)i * ld + c) = v;
}

// ---- transpose weights: src (KH, I, O) fp32 -> dst (KH, O, I) bf16 ----
__global__ void k_wt(const float* __restrict__ src, u16* __restrict__ dst, int I, int O,
                     int total) {
    int idx = blockIdx.x * 256 + threadIdx.x;
    if (idx >= total) return;
    int io = I * O;
    int k = idx / io, rem = idx - k * io;
    int n = rem / I, i = rem - n * I;
    dst[idx] = f2b(src[(size_t)k * io + (size_t)i * O + n]);
}

// ---- W3 (4,512,16) fp32 -> W3T (64, 512) bf16 : W3T[k*16+f][i] = W3[k][i][f] ----
__global__ void k_wt3(const float* __restrict__ W3, u16* __restrict__ W3T) {
    int idx = blockIdx.x * 256 + threadIdx.x;
    if (idx >= 64 * 512) return;
    int n = idx >> 9, i = idx & 511;
    int k = n >> 4, f = n & 15;
    W3T[idx] = f2b(W3[((size_t)k * 512 + i) * 16 + f]);
}

extern "C" void kernel_launch(void* const* d_in, const int* in_sizes, int n_in,
                              void* d_out, int out_size, void* d_ws, size_t ws_size,
                              hipStream_t stream) {
    const float* x = (const float*)d_in[0];
    const int* ei = (const int*)d_in[1];
    const float* W1 = (const float*)d_in[2];
    const float* b1 = (const float*)d_in[3];
    const float* W2 = (const float*)d_in[4];
    const float* b2 = (const float*)d_in[5];
    const float* W3 = (const float*)d_in[6];
    const float* b3 = (const float*)d_in[7];
    const float* g1w = (const float*)d_in[8];
    const float* g1b = (const float*)d_in[9];
    const float* g1a = (const float*)d_in[10];
    const float* g2w = (const float*)d_in[11];
    const float* g2b = (const float*)d_in[12];
    const float* g2a = (const float*)d_in[13];
    const int* row = ei;
    const int* col = ei + EE;

    char* p = (char*)d_ws;
    auto alloc = [&](size_t bytes) {
        char* r = p;
        p += (bytes + 255) & ~(size_t)255;
        return r;
    };
    // Total workspace ~247.5 MB (rounds 8-13 proven budget)
    u16* H1 = (u16*)alloc((size_t)NN * 512 * 2);                  // 102.4 MB: h1 / hop fp8 park
    u16* Y = (u16*)alloc((size_t)NN * 512 * 2);                   // 102.4 MB: L1 scratch -> Y
    unsigned char* X8 = (unsigned char*)alloc((size_t)NN * 256);  // 25.6 MB fp8 width-256
    unsigned int* ep = (unsigned int*)alloc((size_t)EE * 4);      // 12.8 MB
    u16* W1T = (u16*)alloc((size_t)4 * 512 * 128 * 2);            // 0.5 MB
    u16* W2T = (u16*)alloc((size_t)4 * 512 * 512 * 2);            // 2.0 MB
    u16* W3T = (u16*)alloc(64 * 512 * 2);                         // 64 KB
    float* dinv = (float*)alloc((size_t)NN * 4);
    float* stats = (float*)alloc(2048 * 4);
    int* deg = (int*)alloc((size_t)NN * 4);
    int* offs = (int*)alloc((size_t)(NN + 1) * 4);
    int* cursor = (int*)alloc((size_t)NN * 4);
    (void)ws_size;
    (void)in_sizes;
    (void)n_in;
    (void)out_size;

    // L1 scratch parked in Y (dead before L2 GEMM1 writes Y):
    u16* xb = Y;                                                // N x 128 bf16 (25.6 MB)
    unsigned char* F8a = (unsigned char*)Y + (size_t)NN * 256;  // N x 128 fp8
    unsigned char* F8b = (unsigned char*)Y + (size_t)NN * 256 + (size_t)NN * 128;

    // ---- CSR build + weight transpose/convert
    k_init<<<cdiv(NN, 256), 256, 0, stream>>>(deg, cursor, stats);
    k_deg<<<cdiv(EE, 256), 256, 0, stream>>>(col, deg);
    k_dinv<<<cdiv(NN, 256), 256, 0, stream>>>(deg, dinv);
    k_scan<<<1, 1024, 0, stream>>>(deg, offs);
    k_scatter<<<cdiv(EE, 256), 256, 0, stream>>>(row, col, dinv, offs, cursor, ep);
    k_wt<<<cdiv(4 * 128 * 512, 256), 256, 0, stream>>>(W1, W1T, 128, 512, 4 * 128 * 512);
    k_wt<<<cdiv(4 * 512 * 512, 256), 256, 0, stream>>>(W2, W2T, 512, 512, 4 * 512 * 512);
    k_wt3<<<cdiv(64 * 512, 256), 256, 0, stream>>>(W3, W3T);

    dim3 gg(512 / 128, cdiv(NN, 128));     // (4, 782), 128x128 tiles
    const size_t WQ = (size_t)512 * 512;   // per-hop stride in W2T
    const size_t W1Q = (size_t)512 * 128;  // per-hop stride in W1T

    // ---- layer 1 (FUSED): h1 = relu(sum_{k=0..3} (A^k x) W1[k] + b1), one K=512 GEMM.
    // hop3 parks in X8 (dead until layer 2); full fp32 accumulation.
    k_cvt<<<cdiv(NN * 32, 256), 256, 0, stream>>>(x, xb, NN * 32);
    k_prop_t<0><<<NN, 64, 0, stream>>>(xb, 128, F8a, 128, offs, ep);   // hop1 fp8
    k_prop_t<1><<<NN, 64, 0, stream>>>(F8a, 128, F8b, 128, offs, ep);  // hop2 fp8
    k_prop_t<1><<<NN, 64, 0, stream>>>(F8b, 128, X8, 128, offs, ep);   // hop3 fp8 -> X8
    k_gemm_mfma<<<gg, 512, 0, stream>>>(xb, 128, F8a, 128, F8b, 128, X8, 128, 14, W1T,
                                        W1T + W1Q, W1T + 2 * W1Q, W1T + 3 * W1Q, 128, H1, 512,
                                        NN, 512, 512, 128, b1, 1, 1, stats);
    k_gnorm<<<NN, 256, 0, stream>>>(H1, 512, stats, g1w, g1b, g1a);

    // ---- layer 2: Y = relu(sum_k (A^k h1) W2[k] + b2), 2 K-chunks of width 256.
    // Chunk 0: GEMM(k=0) first (frees h1c0 slice to host hops), then K=768 hop GEMM.
    // Chunk 1 (FUSED): hops park in the now-dead h1c0 slice -> one K=1024 GEMM.
    unsigned char* hpA = (unsigned char*)H1;        // chunk-0 slice byte [0,256) per row
    unsigned char* hpB = (unsigned char*)H1 + 256;  // chunk-0 slice byte [256,512) per row
    {
        // chunk 0
        u16* h1c0 = H1;
        k_cvt8s<<<cdiv(NN * 128, 256), 256, 0, stream>>>(h1c0, 512, X8, 256);
        k_gemm_mfma<<<gg, 512, 0, stream>>>(h1c0, 512, h1c0, 512, h1c0, 512, h1c0, 512, 0,
                                            W2T, W2T, W2T, W2T, 512, Y, 512, NN, 512, 256,
                                            256, nullptr, 0, 1, nullptr);
        k_prop256<<<NN, 64, 0, stream>>>(X8, 256, hpA, 1024, offs, ep);    // hop1
        k_prop256<<<NN, 64, 0, stream>>>(hpA, 1024, hpB, 1024, offs, ep);  // hop2
        k_prop256<<<NN, 64, 0, stream>>>(hpB, 1024, X8, 256, offs, ep);    // hop3 (X8 dead)
        k_gemm_mfma<<<gg, 512, 0, stream>>>(hpA, 1024, hpB, 1024, X8, 256, X8, 256, 7,
                                            W2T + WQ, W2T + 2 * WQ, W2T + 3 * WQ, W2T, 512,
                                            Y, 512, NN, 512, 768, 256, nullptr, 0, 2,
                                            nullptr);
    }
    {
        // chunk 1 (fused): h1c1 stays alive (A0); hops reuse dead chunk-0 slice + X8
        u16* h1c1 = H1 + 256;
        k_cvt8s<<<cdiv(NN * 128, 256), 256, 0, stream>>>(h1c1, 512, X8, 256);
        k_prop256<<<NN, 64, 0, stream>>>(X8, 256, hpA, 1024, offs, ep);    // hop1
        k_prop256<<<NN, 64, 0, stream>>>(hpA, 1024, hpB, 1024, offs, ep);  // hop2
        k_prop256<<<NN, 64, 0, stream>>>(hpB, 1024, X8, 256, offs, ep);    // hop3
        k_gemm_mfma<<<gg, 512, 0, stream>>>(h1c1, 512, hpA, 1024, hpB, 1024, X8, 256, 14,
                                            W2T + 256, W2T + WQ + 256, W2T + 2 * WQ + 256,
                                            W2T + 3 * WQ + 256, 512, Y, 512, NN, 512, 1024,
                                            256, b2, 1, 2, stats + 1024);
    }
    k_gnorm<<<NN, 256, 0, stream>>>(Y, 512, stats + 1024, g2w, g2b, g2a);

    // ---- layer 3 (Horner at width 16): G = h2 @ [W3_0|W3_1|W3_2|W3_3] (fp32, H1 dead)
    float* G = (float*)H1;             // N x 64 fp32 = 25.6 MB
    float* tA = (float*)X8;            // N x 16 fp32 = 6.4 MB
    float* tB = tA + (size_t)NN * 16;  // 6.4 MB (X8 = 25.6 MB holds both)
    {
        dim3 g3(1, cdiv(NN, 128));
        k_gemm_mfma<<<g3, 512, 0, stream>>>(Y, 512, Y, 512, Y, 512, Y, 512, 0, W3T, W3T, W3T,
                                            W3T, 512, G, 64, NN, 64, 512, 512, nullptr, 0, 0,
                                            nullptr);
    }
    k_prop16<<<cdiv(NN, 16), 256, 0, stream>>>(G + 48, 64, G + 32, 64, tA, nullptr, offs, ep);
    k_prop16<<<cdiv(NN, 16), 256, 0, stream>>>(tA, 16, G + 16, 64, tB, nullptr, offs, ep);
    k_prop16<<<cdiv(NN, 16), 256, 0, stream>>>(tB, 16, G + 0, 64, (float*)d_out, b3, offs, ep);
}